// Round 1
// baseline (915.558 us; speedup 1.0000x reference)
//
#include <hip/hip_runtime.h>
#include <math.h>

#define N_NODES 100000
#define N_EDGES 800000
#define E_TOT (N_EDGES + N_NODES)
#define NEG_SLOPE 0.2f

static __device__ __forceinline__ float leaky(float e) {
  return e > 0.f ? e : NEG_SLOPE * e;
}

// ---------------- CSR build ----------------

__global__ void degree_kernel(const int* __restrict__ ei, int* __restrict__ deg) {
  int e = blockIdx.x * 256 + threadIdx.x;
  if (e >= E_TOT) return;
  int d = (e < N_EDGES) ? ei[N_EDGES + e] : (e - N_EDGES);
  atomicAdd(&deg[d], 1);
}

__global__ __launch_bounds__(1024) void scan_kernel(const int* __restrict__ deg,
                                                    int* __restrict__ rowptr,
                                                    int* __restrict__ fillpos) {
  __shared__ int sums[1024];
  int tid = threadIdx.x;
  const int chunk = (N_NODES + 1023) / 1024;
  int start = tid * chunk;
  if (start > N_NODES) start = N_NODES;
  int end = start + chunk;
  if (end > N_NODES) end = N_NODES;
  int s = 0;
  for (int i = start; i < end; ++i) s += deg[i];
  sums[tid] = s;
  __syncthreads();
  for (int off = 1; off < 1024; off <<= 1) {
    int v = (tid >= off) ? sums[tid - off] : 0;
    __syncthreads();
    sums[tid] += v;
    __syncthreads();
  }
  int prefix = (tid == 0) ? 0 : sums[tid - 1];
  for (int i = start; i < end; ++i) {
    rowptr[i] = prefix;
    fillpos[i] = prefix;
    prefix += deg[i];
  }
  if (tid == 1023) rowptr[N_NODES] = sums[1023];
}

__global__ void fill_kernel(const int* __restrict__ ei, int* __restrict__ fillpos,
                            int* __restrict__ col) {
  int e = blockIdx.x * 256 + threadIdx.x;
  if (e >= E_TOT) return;
  int s, d;
  if (e < N_EDGES) { s = ei[e]; d = ei[N_EDGES + e]; }
  else { s = d = e - N_EDGES; }
  int p = atomicAdd(&fillpos[d], 1);
  col[p] = s;
}

// ---------------- GEMM (fp32 vector ALU; 64x64 tile, 4x4 micro-tile) ----------------

template <bool RELU_BIAS>
__global__ __launch_bounds__(256) void gemm_kernel(
    const float* __restrict__ A, const float* __restrict__ B,
    const float* __restrict__ bias, float* __restrict__ Out,
    int M, int K, int C) {
  const int KT = 128;
  __shared__ float xs[64][KT + 4];  // +4 pad: compute reads land 2-way (free)
  int tid = threadIdx.x;
  int r0 = (tid >> 4) << 2;
  int c0 = (tid & 15) << 2;
  int Rbase = blockIdx.x * 64;
  int Cbase = blockIdx.y * 64;
  float acc[4][4] = {};
  for (int kc = 0; kc < K; kc += KT) {
    const int F4 = 64 * KT / 4;  // 2048 float4s per tile
    for (int f = tid; f < F4; f += 256) {
      int row = f >> 5;   // KT/4 == 32
      int k4 = f & 31;
      float4 v = make_float4(0.f, 0.f, 0.f, 0.f);
      int grow = Rbase + row;
      if (grow < M)
        v = *reinterpret_cast<const float4*>(&A[(size_t)grow * K + kc + (k4 << 2)]);
      if (RELU_BIAS) {
        float4 bv = *reinterpret_cast<const float4*>(&bias[kc + (k4 << 2)]);
        v.x = fmaxf(v.x + bv.x, 0.f);
        v.y = fmaxf(v.y + bv.y, 0.f);
        v.z = fmaxf(v.z + bv.z, 0.f);
        v.w = fmaxf(v.w + bv.w, 0.f);
      }
      *reinterpret_cast<float4*>(&xs[row][k4 << 2]) = v;
    }
    __syncthreads();
    for (int k4 = 0; k4 < KT / 4; ++k4) {
      float4 a[4], b[4];
#pragma unroll
      for (int i = 0; i < 4; ++i)
        a[i] = *reinterpret_cast<const float4*>(&xs[r0 + i][k4 << 2]);
#pragma unroll
      for (int j = 0; j < 4; ++j)
        b[j] = *reinterpret_cast<const float4*>(
            &B[(size_t)(kc + (k4 << 2) + j) * C + Cbase + c0]);
#pragma unroll
      for (int i = 0; i < 4; ++i) {
        acc[i][0] += a[i].x * b[0].x + a[i].y * b[1].x + a[i].z * b[2].x + a[i].w * b[3].x;
        acc[i][1] += a[i].x * b[0].y + a[i].y * b[1].y + a[i].z * b[2].y + a[i].w * b[3].y;
        acc[i][2] += a[i].x * b[0].z + a[i].y * b[1].z + a[i].z * b[2].z + a[i].w * b[3].z;
        acc[i][3] += a[i].x * b[0].w + a[i].y * b[1].w + a[i].z * b[2].w + a[i].w * b[3].w;
      }
    }
    __syncthreads();
  }
#pragma unroll
  for (int i = 0; i < 4; ++i) {
    int grow = Rbase + r0 + i;
    if (grow < M) {
      float4 v = make_float4(acc[i][0], acc[i][1], acc[i][2], acc[i][3]);
      *reinterpret_cast<float4*>(&Out[(size_t)grow * C + Cbase + c0]) = v;
    }
  }
}

// ---------------- per-node attention scalars ----------------

template <int C>
__global__ __launch_bounds__(256) void alpha_kernel(
    const float* __restrict__ h, const float* __restrict__ vs,
    const float* __restrict__ vd, float* __restrict__ os, float* __restrict__ od) {
  int n = blockIdx.x * 4 + (threadIdx.x >> 6);
  if (n >= N_NODES) return;
  int lane = threadIdx.x & 63;
  float ps = 0.f, pd = 0.f;
#pragma unroll
  for (int c = lane; c < C; c += 64) {
    float v = h[(size_t)n * C + c];
    ps += v * vs[c];
    pd += v * vd[c];
  }
#pragma unroll
  for (int off = 32; off; off >>= 1) {
    ps += __shfl_xor(ps, off);
    pd += __shfl_xor(pd, off);
  }
  if (lane == 0) { os[n] = ps; od[n] = pd; }
}

// per-node softmax over incoming edges; writes normalized alpha per edge
__global__ __launch_bounds__(256) void softmax_prep(
    const int* __restrict__ rowptr, const int* __restrict__ col,
    const float* __restrict__ asrc, const float* __restrict__ adst,
    float* __restrict__ alphaE) {
  int n = blockIdx.x * 4 + (threadIdx.x >> 6);
  if (n >= N_NODES) return;
  int lane = threadIdx.x & 63;
  int beg = rowptr[n], end = rowptr[n + 1];
  float ad = adst[n];
  float m = -1e30f;
  for (int j = beg + lane; j < end; j += 64)
    m = fmaxf(m, leaky(asrc[col[j]] + ad));
#pragma unroll
  for (int off = 32; off; off >>= 1) m = fmaxf(m, __shfl_xor(m, off));
  float ssum = 0.f;
  for (int j = beg + lane; j < end; j += 64)
    ssum += expf(leaky(asrc[col[j]] + ad) - m);
#pragma unroll
  for (int off = 32; off; off >>= 1) ssum += __shfl_xor(ssum, off);
  float inv = 1.0f / ssum;
  for (int j = beg + lane; j < end; j += 64)
    alphaE[j] = expf(leaky(asrc[col[j]] + ad) - m) * inv;
}

// ---------------- aggregation ----------------

// layer 1: one block per node, thread = channel (C=256)
__global__ __launch_bounds__(256) void aggregate_c256(
    const float* __restrict__ h, const int* __restrict__ rowptr,
    const int* __restrict__ col, const float* __restrict__ alphaE,
    float* __restrict__ out) {
  int n = blockIdx.x;
  int c = threadIdx.x;
  int beg = rowptr[n], end = rowptr[n + 1];
  float acc = 0.f;
  for (int j = beg; j < end; ++j) {
    int s = col[j];
    float al = alphaE[j];
    acc += al * h[(size_t)s * 256 + c];
  }
  out[(size_t)n * 256 + c] = acc;
}

// layer 2: wave per node (C=64), fused +bias, writes final output
__global__ __launch_bounds__(256) void aggregate_c64(
    const float* __restrict__ h, const int* __restrict__ rowptr,
    const int* __restrict__ col, const float* __restrict__ alphaE,
    const float* __restrict__ bias, float* __restrict__ out) {
  int n = blockIdx.x * 4 + (threadIdx.x >> 6);
  if (n >= N_NODES) return;
  int lane = threadIdx.x & 63;
  int beg = rowptr[n], end = rowptr[n + 1];
  float acc = 0.f;
  for (int j = beg; j < end; ++j)
    acc += alphaE[j] * h[(size_t)col[j] * 64 + lane];
  out[(size_t)n * 64 + lane] = acc + bias[lane];
}

// ---------------- launch ----------------

extern "C" void kernel_launch(void* const* d_in, const int* in_sizes, int n_in,
                              void* d_out, int out_size, void* d_ws, size_t ws_size,
                              hipStream_t stream) {
  const float* x    = (const float*)d_in[0];
  const int*   ei   = (const int*)d_in[1];
  const float* W1   = (const float*)d_in[2];
  const float* a1s  = (const float*)d_in[3];
  const float* a1d  = (const float*)d_in[4];
  const float* b1   = (const float*)d_in[5];
  const float* W2   = (const float*)d_in[6];
  const float* a2s  = (const float*)d_in[7];
  const float* a2d  = (const float*)d_in[8];
  const float* b2   = (const float*)d_in[9];
  float* out = (float*)d_out;

  char* ws = (char*)d_ws;
  size_t off = 0;
  auto alloc = [&](size_t bytes) {
    void* p = ws + off;
    off += bytes;
    off = (off + 255) & ~(size_t)255;
    return p;
  };

  float* h1     = (float*)alloc((size_t)N_NODES * 256 * 4);
  float* agg1   = (float*)alloc((size_t)N_NODES * 256 * 4);
  float* h2     = (float*)alloc((size_t)N_NODES * 64 * 4);
  float* asrc1  = (float*)alloc((size_t)N_NODES * 4);
  float* adst1  = (float*)alloc((size_t)N_NODES * 4);
  float* asrc2  = (float*)alloc((size_t)N_NODES * 4);
  float* adst2  = (float*)alloc((size_t)N_NODES * 4);
  float* alphaE = (float*)alloc((size_t)E_TOT * 4);
  int*   deg    = (int*)alloc((size_t)N_NODES * 4);
  int*   rowptr = (int*)alloc((size_t)(N_NODES + 1) * 4);
  int*   fillp  = (int*)alloc((size_t)N_NODES * 4);
  int*   col    = (int*)alloc((size_t)E_TOT * 4);

  const int edgeBlocks = (E_TOT + 255) / 256;
  const int nodeBlocks4 = (N_NODES + 3) / 4;

  // CSR build
  hipMemsetAsync(deg, 0, (size_t)N_NODES * 4, stream);
  degree_kernel<<<edgeBlocks, 256, 0, stream>>>(ei, deg);
  scan_kernel<<<1, 1024, 0, stream>>>(deg, rowptr, fillp);
  fill_kernel<<<edgeBlocks, 256, 0, stream>>>(ei, fillp, col);

  // layer 1
  gemm_kernel<false><<<dim3((N_NODES + 63) / 64, 256 / 64), 256, 0, stream>>>(
      x, W1, nullptr, h1, N_NODES, 128, 256);
  alpha_kernel<256><<<nodeBlocks4, 256, 0, stream>>>(h1, a1s, a1d, asrc1, adst1);
  softmax_prep<<<nodeBlocks4, 256, 0, stream>>>(rowptr, col, asrc1, adst1, alphaE);
  aggregate_c256<<<N_NODES, 256, 0, stream>>>(h1, rowptr, col, alphaE, agg1);

  // layer 2 (relu(agg1 + b1) fused into GEMM2 A-tile load)
  gemm_kernel<true><<<dim3((N_NODES + 63) / 64, 64 / 64), 256, 0, stream>>>(
      agg1, W2, b1, h2, N_NODES, 256, 64);
  alpha_kernel<64><<<nodeBlocks4, 256, 0, stream>>>(h2, a2s, a2d, asrc2, adst2);
  softmax_prep<<<nodeBlocks4, 256, 0, stream>>>(rowptr, col, asrc2, adst2, alphaE);
  aggregate_c64<<<nodeBlocks4, 256, 0, stream>>>(h2, rowptr, col, alphaE, b2, out);
}

// Round 2
// 698.842 us; speedup vs baseline: 1.3101x; 1.3101x over previous
//
#include <hip/hip_runtime.h>
#include <math.h>

#define N_NODES 100000
#define N_EDGES 800000
#define E_TOT (N_EDGES + N_NODES)
#define NEG_SLOPE 0.2f
#define SCAN_NB ((N_NODES + 1023) / 1024)

static __device__ __forceinline__ float leaky(float e) {
  return e > 0.f ? e : NEG_SLOPE * e;
}

// ---------------- CSR build ----------------

__global__ void degree_kernel(const int* __restrict__ ei, int* __restrict__ deg) {
  int e = blockIdx.x * 256 + threadIdx.x;
  if (e >= E_TOT) return;
  int d = (e < N_EDGES) ? ei[N_EDGES + e] : (e - N_EDGES);
  atomicAdd(&deg[d], 1);
}

// 3-phase device-wide exclusive scan of deg -> rowptr/fillpos
__global__ __launch_bounds__(1024) void scan_p1(const int* __restrict__ deg,
                                                int* __restrict__ blockSums) {
  int i = blockIdx.x * 1024 + threadIdx.x;
  int v = (i < N_NODES) ? deg[i] : 0;
#pragma unroll
  for (int off = 32; off; off >>= 1) v += __shfl_xor(v, off);
  __shared__ int wsum[16];
  if ((threadIdx.x & 63) == 0) wsum[threadIdx.x >> 6] = v;
  __syncthreads();
  if (threadIdx.x == 0) {
    int s = 0;
#pragma unroll
    for (int w = 0; w < 16; ++w) s += wsum[w];
    blockSums[blockIdx.x] = s;
  }
}

__global__ void scan_p2(const int* __restrict__ blockSums, int* __restrict__ blockOffs) {
  if (threadIdx.x == 0) {
    int s = 0;
    for (int b = 0; b < SCAN_NB; ++b) { blockOffs[b] = s; s += blockSums[b]; }
  }
}

__global__ __launch_bounds__(1024) void scan_p3(const int* __restrict__ deg,
                                                const int* __restrict__ blockOffs,
                                                int* __restrict__ rowptr,
                                                int* __restrict__ fillpos) {
  __shared__ int sh[1024];
  int i = blockIdx.x * 1024 + threadIdx.x;
  int v = (i < N_NODES) ? deg[i] : 0;
  sh[threadIdx.x] = v;
  __syncthreads();
  for (int off = 1; off < 1024; off <<= 1) {
    int t = (threadIdx.x >= off) ? sh[threadIdx.x - off] : 0;
    __syncthreads();
    sh[threadIdx.x] += t;
    __syncthreads();
  }
  if (i < N_NODES) {
    int excl = sh[threadIdx.x] - v + blockOffs[blockIdx.x];
    rowptr[i] = excl;
    fillpos[i] = excl;
    if (i == N_NODES - 1) rowptr[N_NODES] = excl + v;
  }
}

__global__ void fill_kernel(const int* __restrict__ ei, int* __restrict__ fillpos,
                            int* __restrict__ col) {
  int e = blockIdx.x * 256 + threadIdx.x;
  if (e >= E_TOT) return;
  int s, d;
  if (e < N_EDGES) { s = ei[e]; d = ei[N_EDGES + e]; }
  else { s = d = e - N_EDGES; }
  int p = atomicAdd(&fillpos[d], 1);
  col[p] = s;
}

// ---------------- GEMM (fp32 vector ALU; 64x64 tile, 4x4 micro-tile) ----------------

template <bool RELU_BIAS>
__global__ __launch_bounds__(256) void gemm_kernel(
    const float* __restrict__ A, const float* __restrict__ B,
    const float* __restrict__ bias, float* __restrict__ Out,
    int M, int K, int C) {
  const int KT = 128;
  __shared__ float xs[64][KT + 4];  // +4 pad: compute reads land 2-way (free)
  int tid = threadIdx.x;
  int r0 = (tid >> 4) << 2;
  int c0 = (tid & 15) << 2;
  int Rbase = blockIdx.x * 64;
  int Cbase = blockIdx.y * 64;
  float acc[4][4] = {};
  for (int kc = 0; kc < K; kc += KT) {
    const int F4 = 64 * KT / 4;  // 2048 float4s per tile
    for (int f = tid; f < F4; f += 256) {
      int row = f >> 5;   // KT/4 == 32
      int k4 = f & 31;
      float4 v = make_float4(0.f, 0.f, 0.f, 0.f);
      int grow = Rbase + row;
      if (grow < M)
        v = *reinterpret_cast<const float4*>(&A[(size_t)grow * K + kc + (k4 << 2)]);
      if (RELU_BIAS) {
        float4 bv = *reinterpret_cast<const float4*>(&bias[kc + (k4 << 2)]);
        v.x = fmaxf(v.x + bv.x, 0.f);
        v.y = fmaxf(v.y + bv.y, 0.f);
        v.z = fmaxf(v.z + bv.z, 0.f);
        v.w = fmaxf(v.w + bv.w, 0.f);
      }
      *reinterpret_cast<float4*>(&xs[row][k4 << 2]) = v;
    }
    __syncthreads();
    for (int k4 = 0; k4 < KT / 4; ++k4) {
      float4 a[4], b[4];
#pragma unroll
      for (int i = 0; i < 4; ++i)
        a[i] = *reinterpret_cast<const float4*>(&xs[r0 + i][k4 << 2]);
#pragma unroll
      for (int j = 0; j < 4; ++j)
        b[j] = *reinterpret_cast<const float4*>(
            &B[(size_t)(kc + (k4 << 2) + j) * C + Cbase + c0]);
#pragma unroll
      for (int i = 0; i < 4; ++i) {
        acc[i][0] += a[i].x * b[0].x + a[i].y * b[1].x + a[i].z * b[2].x + a[i].w * b[3].x;
        acc[i][1] += a[i].x * b[0].y + a[i].y * b[1].y + a[i].z * b[2].y + a[i].w * b[3].y;
        acc[i][2] += a[i].x * b[0].z + a[i].y * b[1].z + a[i].z * b[2].z + a[i].w * b[3].z;
        acc[i][3] += a[i].x * b[0].w + a[i].y * b[1].w + a[i].z * b[2].w + a[i].w * b[3].w;
      }
    }
    __syncthreads();
  }
#pragma unroll
  for (int i = 0; i < 4; ++i) {
    int grow = Rbase + r0 + i;
    if (grow < M) {
      float4 v = make_float4(acc[i][0], acc[i][1], acc[i][2], acc[i][3]);
      *reinterpret_cast<float4*>(&Out[(size_t)grow * C + Cbase + c0]) = v;
    }
  }
}

// ---------------- per-node attention scalars ----------------

template <int C>
__global__ __launch_bounds__(256) void alpha_kernel(
    const float* __restrict__ h, const float* __restrict__ vs,
    const float* __restrict__ vd, float* __restrict__ os, float* __restrict__ od) {
  int n = blockIdx.x * 4 + (threadIdx.x >> 6);
  if (n >= N_NODES) return;
  int lane = threadIdx.x & 63;
  float ps = 0.f, pd = 0.f;
#pragma unroll
  for (int c = lane; c < C; c += 64) {
    float v = h[(size_t)n * C + c];
    ps += v * vs[c];
    pd += v * vd[c];
  }
#pragma unroll
  for (int off = 32; off; off >>= 1) {
    ps += __shfl_xor(ps, off);
    pd += __shfl_xor(pd, off);
  }
  if (lane == 0) { os[n] = ps; od[n] = pd; }
}

// per-node softmax over incoming edges; writes normalized alpha per edge
__global__ __launch_bounds__(256) void softmax_prep(
    const int* __restrict__ rowptr, const int* __restrict__ col,
    const float* __restrict__ asrc, const float* __restrict__ adst,
    float* __restrict__ alphaE) {
  int n = blockIdx.x * 4 + (threadIdx.x >> 6);
  if (n >= N_NODES) return;
  int lane = threadIdx.x & 63;
  int beg = rowptr[n], end = rowptr[n + 1];
  float ad = adst[n];
  float m = -1e30f;
  for (int j = beg + lane; j < end; j += 64)
    m = fmaxf(m, leaky(asrc[col[j]] + ad));
#pragma unroll
  for (int off = 32; off; off >>= 1) m = fmaxf(m, __shfl_xor(m, off));
  float ssum = 0.f;
  for (int j = beg + lane; j < end; j += 64)
    ssum += expf(leaky(asrc[col[j]] + ad) - m);
#pragma unroll
  for (int off = 32; off; off >>= 1) ssum += __shfl_xor(ssum, off);
  float inv = 1.0f / ssum;
  for (int j = beg + lane; j < end; j += 64)
    alphaE[j] = expf(leaky(asrc[col[j]] + ad) - m) * inv;
}

// ---------------- aggregation ----------------

// layer 1: one block per node, thread = channel (C=256)
__global__ __launch_bounds__(256) void aggregate_c256(
    const float* __restrict__ h, const int* __restrict__ rowptr,
    const int* __restrict__ col, const float* __restrict__ alphaE,
    float* __restrict__ out) {
  int n = blockIdx.x;
  int c = threadIdx.x;
  int beg = rowptr[n], end = rowptr[n + 1];
  float acc = 0.f;
  for (int j = beg; j < end; ++j) {
    int s = col[j];
    float al = alphaE[j];
    acc += al * h[(size_t)s * 256 + c];
  }
  out[(size_t)n * 256 + c] = acc;
}

// layer 2: wave per node (C=64), fused +bias, writes final output
__global__ __launch_bounds__(256) void aggregate_c64(
    const float* __restrict__ h, const int* __restrict__ rowptr,
    const int* __restrict__ col, const float* __restrict__ alphaE,
    const float* __restrict__ bias, float* __restrict__ out) {
  int n = blockIdx.x * 4 + (threadIdx.x >> 6);
  if (n >= N_NODES) return;
  int lane = threadIdx.x & 63;
  int beg = rowptr[n], end = rowptr[n + 1];
  float acc = 0.f;
  for (int j = beg; j < end; ++j)
    acc += alphaE[j] * h[(size_t)col[j] * 64 + lane];
  out[(size_t)n * 64 + lane] = acc + bias[lane];
}

// ---------------- launch ----------------

extern "C" void kernel_launch(void* const* d_in, const int* in_sizes, int n_in,
                              void* d_out, int out_size, void* d_ws, size_t ws_size,
                              hipStream_t stream) {
  const float* x    = (const float*)d_in[0];
  const int*   ei   = (const int*)d_in[1];
  const float* W1   = (const float*)d_in[2];
  const float* a1s  = (const float*)d_in[3];
  const float* a1d  = (const float*)d_in[4];
  const float* b1   = (const float*)d_in[5];
  const float* W2   = (const float*)d_in[6];
  const float* a2s  = (const float*)d_in[7];
  const float* a2d  = (const float*)d_in[8];
  const float* b2   = (const float*)d_in[9];
  float* out = (float*)d_out;

  char* ws = (char*)d_ws;
  size_t off = 0;
  auto alloc = [&](size_t bytes) {
    void* p = ws + off;
    off += bytes;
    off = (off + 255) & ~(size_t)255;
    return p;
  };

  float* h1     = (float*)alloc((size_t)N_NODES * 256 * 4);
  float* agg1   = (float*)alloc((size_t)N_NODES * 256 * 4);
  float* h2     = (float*)alloc((size_t)N_NODES * 64 * 4);
  float* asrc1  = (float*)alloc((size_t)N_NODES * 4);
  float* adst1  = (float*)alloc((size_t)N_NODES * 4);
  float* asrc2  = (float*)alloc((size_t)N_NODES * 4);
  float* adst2  = (float*)alloc((size_t)N_NODES * 4);
  float* alphaE = (float*)alloc((size_t)E_TOT * 4);
  int*   deg    = (int*)alloc((size_t)N_NODES * 4);
  int*   rowptr = (int*)alloc((size_t)(N_NODES + 1) * 4);
  int*   fillp  = (int*)alloc((size_t)N_NODES * 4);
  int*   col    = (int*)alloc((size_t)E_TOT * 4);
  int*   bsums  = (int*)alloc((size_t)SCAN_NB * 4);
  int*   boffs  = (int*)alloc((size_t)SCAN_NB * 4);

  const int edgeBlocks = (E_TOT + 255) / 256;
  const int nodeBlocks4 = (N_NODES + 3) / 4;

  // CSR build
  hipMemsetAsync(deg, 0, (size_t)N_NODES * 4, stream);
  degree_kernel<<<edgeBlocks, 256, 0, stream>>>(ei, deg);
  scan_p1<<<SCAN_NB, 1024, 0, stream>>>(deg, bsums);
  scan_p2<<<1, 64, 0, stream>>>(bsums, boffs);
  scan_p3<<<SCAN_NB, 1024, 0, stream>>>(deg, boffs, rowptr, fillp);
  fill_kernel<<<edgeBlocks, 256, 0, stream>>>(ei, fillp, col);

  // layer 1
  gemm_kernel<false><<<dim3((N_NODES + 63) / 64, 256 / 64), 256, 0, stream>>>(
      x, W1, nullptr, h1, N_NODES, 128, 256);
  alpha_kernel<256><<<nodeBlocks4, 256, 0, stream>>>(h1, a1s, a1d, asrc1, adst1);
  softmax_prep<<<nodeBlocks4, 256, 0, stream>>>(rowptr, col, asrc1, adst1, alphaE);
  aggregate_c256<<<N_NODES, 256, 0, stream>>>(h1, rowptr, col, alphaE, agg1);

  // layer 2 (relu(agg1 + b1) fused into GEMM2 A-tile load)
  gemm_kernel<true><<<dim3((N_NODES + 63) / 64, 64 / 64), 256, 0, stream>>>(
      agg1, W2, b1, h2, N_NODES, 256, 64);
  alpha_kernel<64><<<nodeBlocks4, 256, 0, stream>>>(h2, a2s, a2d, asrc2, adst2);
  softmax_prep<<<nodeBlocks4, 256, 0, stream>>>(rowptr, col, asrc2, adst2, alphaE);
  aggregate_c64<<<nodeBlocks4, 256, 0, stream>>>(h2, rowptr, col, alphaE, b2, out);
}

// Round 3
// 598.540 us; speedup vs baseline: 1.5297x; 1.1676x over previous
//
#include <hip/hip_runtime.h>
#include <math.h>

#define N_NODES 100000
#define N_EDGES 800000
#define E_TOT (N_EDGES + N_NODES)
#define NEG_SLOPE 0.2f
#define SCAN_NB ((N_NODES + 1023) / 1024)

typedef unsigned short ushort_t;

static __device__ __forceinline__ float leaky(float e) {
  return e > 0.f ? e : NEG_SLOPE * e;
}

static __device__ __forceinline__ float b2f(ushort_t u) {
  union { unsigned int i; float f; } x;
  x.i = ((unsigned int)u) << 16;
  return x.f;
}

static __device__ __forceinline__ ushort_t f2b(float f) {
  union { float f; unsigned int i; } x;
  x.f = f;
  unsigned int r = x.i + 0x7FFFu + ((x.i >> 16) & 1u);  // RNE (finite inputs)
  return (ushort_t)(r >> 16);
}

// ---------------- CSR build ----------------

__global__ void degree_kernel(const int* __restrict__ ei, int* __restrict__ deg) {
  int e = blockIdx.x * 256 + threadIdx.x;
  if (e >= E_TOT) return;
  int d = (e < N_EDGES) ? ei[N_EDGES + e] : (e - N_EDGES);
  atomicAdd(&deg[d], 1);
}

__global__ __launch_bounds__(1024) void scan_p1(const int* __restrict__ deg,
                                                int* __restrict__ blockSums) {
  int i = blockIdx.x * 1024 + threadIdx.x;
  int v = (i < N_NODES) ? deg[i] : 0;
#pragma unroll
  for (int off = 32; off; off >>= 1) v += __shfl_xor(v, off);
  __shared__ int wsum[16];
  if ((threadIdx.x & 63) == 0) wsum[threadIdx.x >> 6] = v;
  __syncthreads();
  if (threadIdx.x == 0) {
    int s = 0;
#pragma unroll
    for (int w = 0; w < 16; ++w) s += wsum[w];
    blockSums[blockIdx.x] = s;
  }
}

__global__ void scan_p2(const int* __restrict__ blockSums, int* __restrict__ blockOffs) {
  if (threadIdx.x == 0) {
    int s = 0;
    for (int b = 0; b < SCAN_NB; ++b) { blockOffs[b] = s; s += blockSums[b]; }
  }
}

__global__ __launch_bounds__(1024) void scan_p3(const int* __restrict__ deg,
                                                const int* __restrict__ blockOffs,
                                                int* __restrict__ rowptr,
                                                int* __restrict__ fillpos) {
  __shared__ int sh[1024];
  int i = blockIdx.x * 1024 + threadIdx.x;
  int v = (i < N_NODES) ? deg[i] : 0;
  sh[threadIdx.x] = v;
  __syncthreads();
  for (int off = 1; off < 1024; off <<= 1) {
    int t = (threadIdx.x >= off) ? sh[threadIdx.x - off] : 0;
    __syncthreads();
    sh[threadIdx.x] += t;
    __syncthreads();
  }
  if (i < N_NODES) {
    int excl = sh[threadIdx.x] - v + blockOffs[blockIdx.x];
    rowptr[i] = excl;
    fillpos[i] = excl;
    if (i == N_NODES - 1) rowptr[N_NODES] = excl + v;
  }
}

__global__ void fill_kernel(const int* __restrict__ ei, int* __restrict__ fillpos,
                            int* __restrict__ col) {
  int e = blockIdx.x * 256 + threadIdx.x;
  if (e >= E_TOT) return;
  int s, d;
  if (e < N_EDGES) { s = ei[e]; d = ei[N_EDGES + e]; }
  else { s = d = e - N_EDGES; }
  int p = atomicAdd(&fillpos[d], 1);
  col[p] = s;
}

// ---------------- GEMM (fp32 vector ALU; 64x64 tile, 4x4 micro-tile; bf16 out) ----------------

template <bool RELU_BIAS>
__global__ __launch_bounds__(256) void gemm_kernel(
    const float* __restrict__ A, const float* __restrict__ B,
    const float* __restrict__ bias, ushort_t* __restrict__ Out,
    int M, int K, int C) {
  const int KT = 128;
  __shared__ float xs[64][KT + 4];
  int tid = threadIdx.x;
  int r0 = (tid >> 4) << 2;
  int c0 = (tid & 15) << 2;
  int Rbase = blockIdx.x * 64;
  int Cbase = blockIdx.y * 64;
  float acc[4][4] = {};
  for (int kc = 0; kc < K; kc += KT) {
    const int F4 = 64 * KT / 4;
    for (int f = tid; f < F4; f += 256) {
      int row = f >> 5;
      int k4 = f & 31;
      float4 v = make_float4(0.f, 0.f, 0.f, 0.f);
      int grow = Rbase + row;
      if (grow < M)
        v = *reinterpret_cast<const float4*>(&A[(size_t)grow * K + kc + (k4 << 2)]);
      if (RELU_BIAS) {
        float4 bv = *reinterpret_cast<const float4*>(&bias[kc + (k4 << 2)]);
        v.x = fmaxf(v.x + bv.x, 0.f);
        v.y = fmaxf(v.y + bv.y, 0.f);
        v.z = fmaxf(v.z + bv.z, 0.f);
        v.w = fmaxf(v.w + bv.w, 0.f);
      }
      *reinterpret_cast<float4*>(&xs[row][k4 << 2]) = v;
    }
    __syncthreads();
    for (int k4 = 0; k4 < KT / 4; ++k4) {
      float4 a[4], b[4];
#pragma unroll
      for (int i = 0; i < 4; ++i)
        a[i] = *reinterpret_cast<const float4*>(&xs[r0 + i][k4 << 2]);
#pragma unroll
      for (int j = 0; j < 4; ++j)
        b[j] = *reinterpret_cast<const float4*>(
            &B[(size_t)(kc + (k4 << 2) + j) * C + Cbase + c0]);
#pragma unroll
      for (int i = 0; i < 4; ++i) {
        acc[i][0] += a[i].x * b[0].x + a[i].y * b[1].x + a[i].z * b[2].x + a[i].w * b[3].x;
        acc[i][1] += a[i].x * b[0].y + a[i].y * b[1].y + a[i].z * b[2].y + a[i].w * b[3].y;
        acc[i][2] += a[i].x * b[0].z + a[i].y * b[1].z + a[i].z * b[2].z + a[i].w * b[3].z;
        acc[i][3] += a[i].x * b[0].w + a[i].y * b[1].w + a[i].z * b[2].w + a[i].w * b[3].w;
      }
    }
    __syncthreads();
  }
#pragma unroll
  for (int i = 0; i < 4; ++i) {
    int grow = Rbase + r0 + i;
    if (grow < M) {
      ushort4 v;
      v.x = f2b(acc[i][0]);
      v.y = f2b(acc[i][1]);
      v.z = f2b(acc[i][2]);
      v.w = f2b(acc[i][3]);
      *reinterpret_cast<ushort4*>(&Out[(size_t)grow * C + Cbase + c0]) = v;
    }
  }
}

// ---------------- per-node attention scalars (bf16 h) ----------------

template <int C>
__global__ __launch_bounds__(256) void alpha_kernel(
    const ushort_t* __restrict__ h, const float* __restrict__ vs,
    const float* __restrict__ vd, float* __restrict__ os, float* __restrict__ od) {
  int n = blockIdx.x * 4 + (threadIdx.x >> 6);
  if (n >= N_NODES) return;
  int lane = threadIdx.x & 63;
  float ps = 0.f, pd = 0.f;
  if (C == 256) {
    ushort4 u = *reinterpret_cast<const ushort4*>(&h[(size_t)n * 256 + lane * 4]);
    float f0 = b2f(u.x), f1 = b2f(u.y), f2 = b2f(u.z), f3 = b2f(u.w);
    ps = f0 * vs[lane * 4] + f1 * vs[lane * 4 + 1] + f2 * vs[lane * 4 + 2] + f3 * vs[lane * 4 + 3];
    pd = f0 * vd[lane * 4] + f1 * vd[lane * 4 + 1] + f2 * vd[lane * 4 + 2] + f3 * vd[lane * 4 + 3];
  } else {
    float f = b2f(h[(size_t)n * 64 + lane]);
    ps = f * vs[lane];
    pd = f * vd[lane];
  }
#pragma unroll
  for (int off = 32; off; off >>= 1) {
    ps += __shfl_xor(ps, off);
    pd += __shfl_xor(pd, off);
  }
  if (lane == 0) { os[n] = ps; od[n] = pd; }
}

// per-node softmax over incoming edges; writes normalized alpha per edge
__global__ __launch_bounds__(256) void softmax_prep(
    const int* __restrict__ rowptr, const int* __restrict__ col,
    const float* __restrict__ asrc, const float* __restrict__ adst,
    float* __restrict__ alphaE) {
  int n = blockIdx.x * 4 + (threadIdx.x >> 6);
  if (n >= N_NODES) return;
  int lane = threadIdx.x & 63;
  int beg = rowptr[n], end = rowptr[n + 1];
  float ad = adst[n];
  float m = -1e30f;
  for (int j = beg + lane; j < end; j += 64)
    m = fmaxf(m, leaky(asrc[col[j]] + ad));
#pragma unroll
  for (int off = 32; off; off >>= 1) m = fmaxf(m, __shfl_xor(m, off));
  float ssum = 0.f;
  for (int j = beg + lane; j < end; j += 64)
    ssum += expf(leaky(asrc[col[j]] + ad) - m);
#pragma unroll
  for (int off = 32; off; off >>= 1) ssum += __shfl_xor(ssum, off);
  float inv = 1.0f / ssum;
  for (int j = beg + lane; j < end; j += 64)
    alphaE[j] = expf(leaky(asrc[col[j]] + ad) - m) * inv;
}

// ---------------- aggregation (bf16 h gathers, fp32 accum) ----------------

// layer 1: wave per node, lane = 4 channels (ushort4 = 8B, 512B/wave/edge)
__global__ __launch_bounds__(256) void aggregate1(
    const ushort_t* __restrict__ h, const int* __restrict__ rowptr,
    const int* __restrict__ col, const float* __restrict__ alphaE,
    float* __restrict__ out) {
  int n = blockIdx.x * 4 + (threadIdx.x >> 6);
  if (n >= N_NODES) return;
  int lane = threadIdx.x & 63;
  int beg = rowptr[n], end = rowptr[n + 1];
  float a0 = 0.f, a1 = 0.f, a2 = 0.f, a3 = 0.f;
  for (int j = beg; j < end; ++j) {
    int s = col[j];
    float al = alphaE[j];
    ushort4 u = *reinterpret_cast<const ushort4*>(&h[(size_t)s * 256 + lane * 4]);
    a0 += al * b2f(u.x);
    a1 += al * b2f(u.y);
    a2 += al * b2f(u.z);
    a3 += al * b2f(u.w);
  }
  float4 v = make_float4(a0, a1, a2, a3);
  *reinterpret_cast<float4*>(&out[(size_t)n * 256 + lane * 4]) = v;
}

// layer 2: wave per node (C=64), bf16 gathers, fused +bias, final output
__global__ __launch_bounds__(256) void aggregate2(
    const ushort_t* __restrict__ h, const int* __restrict__ rowptr,
    const int* __restrict__ col, const float* __restrict__ alphaE,
    const float* __restrict__ bias, float* __restrict__ out) {
  int n = blockIdx.x * 4 + (threadIdx.x >> 6);
  if (n >= N_NODES) return;
  int lane = threadIdx.x & 63;
  int beg = rowptr[n], end = rowptr[n + 1];
  float acc = 0.f;
  for (int j = beg; j < end; ++j)
    acc += alphaE[j] * b2f(h[(size_t)col[j] * 64 + lane]);
  out[(size_t)n * 64 + lane] = acc + bias[lane];
}

// ---------------- launch ----------------

extern "C" void kernel_launch(void* const* d_in, const int* in_sizes, int n_in,
                              void* d_out, int out_size, void* d_ws, size_t ws_size,
                              hipStream_t stream) {
  const float* x    = (const float*)d_in[0];
  const int*   ei   = (const int*)d_in[1];
  const float* W1   = (const float*)d_in[2];
  const float* a1s  = (const float*)d_in[3];
  const float* a1d  = (const float*)d_in[4];
  const float* b1   = (const float*)d_in[5];
  const float* W2   = (const float*)d_in[6];
  const float* a2s  = (const float*)d_in[7];
  const float* a2d  = (const float*)d_in[8];
  const float* b2   = (const float*)d_in[9];
  float* out = (float*)d_out;

  char* ws = (char*)d_ws;
  size_t off = 0;
  auto alloc = [&](size_t bytes) {
    void* p = ws + off;
    off += bytes;
    off = (off + 255) & ~(size_t)255;
    return p;
  };

  ushort_t* h1  = (ushort_t*)alloc((size_t)N_NODES * 256 * 2);  // bf16
  float* agg1   = (float*)alloc((size_t)N_NODES * 256 * 4);
  ushort_t* h2  = (ushort_t*)alloc((size_t)N_NODES * 64 * 2);   // bf16
  float* asrc1  = (float*)alloc((size_t)N_NODES * 4);
  float* adst1  = (float*)alloc((size_t)N_NODES * 4);
  float* asrc2  = (float*)alloc((size_t)N_NODES * 4);
  float* adst2  = (float*)alloc((size_t)N_NODES * 4);
  float* alphaE = (float*)alloc((size_t)E_TOT * 4);
  int*   deg    = (int*)alloc((size_t)N_NODES * 4);
  int*   rowptr = (int*)alloc((size_t)(N_NODES + 1) * 4);
  int*   fillp  = (int*)alloc((size_t)N_NODES * 4);
  int*   col    = (int*)alloc((size_t)E_TOT * 4);
  int*   bsums  = (int*)alloc((size_t)SCAN_NB * 4);
  int*   boffs  = (int*)alloc((size_t)SCAN_NB * 4);

  const int edgeBlocks = (E_TOT + 255) / 256;
  const int nodeBlocks4 = (N_NODES + 3) / 4;

  // CSR build
  hipMemsetAsync(deg, 0, (size_t)N_NODES * 4, stream);
  degree_kernel<<<edgeBlocks, 256, 0, stream>>>(ei, deg);
  scan_p1<<<SCAN_NB, 1024, 0, stream>>>(deg, bsums);
  scan_p2<<<1, 64, 0, stream>>>(bsums, boffs);
  scan_p3<<<SCAN_NB, 1024, 0, stream>>>(deg, boffs, rowptr, fillp);
  fill_kernel<<<edgeBlocks, 256, 0, stream>>>(ei, fillp, col);

  // layer 1
  gemm_kernel<false><<<dim3((N_NODES + 63) / 64, 256 / 64), 256, 0, stream>>>(
      x, W1, nullptr, h1, N_NODES, 128, 256);
  alpha_kernel<256><<<nodeBlocks4, 256, 0, stream>>>(h1, a1s, a1d, asrc1, adst1);
  softmax_prep<<<nodeBlocks4, 256, 0, stream>>>(rowptr, col, asrc1, adst1, alphaE);
  aggregate1<<<nodeBlocks4, 256, 0, stream>>>(h1, rowptr, col, alphaE, agg1);

  // layer 2 (relu(agg1 + b1) fused into GEMM2 A-tile load)
  gemm_kernel<true><<<dim3((N_NODES + 63) / 64, 64 / 64), 256, 0, stream>>>(
      agg1, W2, b1, h2, N_NODES, 256, 64);
  alpha_kernel<64><<<nodeBlocks4, 256, 0, stream>>>(h2, a2s, a2d, asrc2, adst2);
  softmax_prep<<<nodeBlocks4, 256, 0, stream>>>(rowptr, col, asrc2, adst2, alphaE);
  aggregate2<<<nodeBlocks4, 256, 0, stream>>>(h2, rowptr, col, alphaE, b2, out);
}

// Round 4
// 474.665 us; speedup vs baseline: 1.9289x; 1.2610x over previous
//
#include <hip/hip_runtime.h>
#include <math.h>

#define N_NODES 100000
#define N_EDGES 800000
#define E_TOT (N_EDGES + N_NODES)
#define NEG_SLOPE 0.2f
#define SCAN_NB ((N_NODES + 1023) / 1024)

typedef unsigned short ushort_t;
typedef __attribute__((ext_vector_type(8))) short short8v;   // 8 bf16
typedef __attribute__((ext_vector_type(4))) float f32x4;

static __device__ __forceinline__ float leaky(float e) {
  return e > 0.f ? e : NEG_SLOPE * e;
}

static __device__ __forceinline__ float b2f(ushort_t u) {
  union { unsigned int i; float f; } x;
  x.i = ((unsigned int)u) << 16;
  return x.f;
}

static __device__ __forceinline__ ushort_t f2b(float f) {
  union { float f; unsigned int i; } x;
  x.f = f;
  unsigned int r = x.i + 0x7FFFu + ((x.i >> 16) & 1u);  // RNE (finite inputs)
  return (ushort_t)(r >> 16);
}

// ---------------- CSR build ----------------

__global__ void degree_kernel(const int* __restrict__ ei, int* __restrict__ deg) {
  int e = blockIdx.x * 256 + threadIdx.x;
  if (e >= E_TOT) return;
  int d = (e < N_EDGES) ? ei[N_EDGES + e] : (e - N_EDGES);
  atomicAdd(&deg[d], 1);
}

__global__ __launch_bounds__(1024) void scan_p1(const int* __restrict__ deg,
                                                int* __restrict__ blockSums) {
  int i = blockIdx.x * 1024 + threadIdx.x;
  int v = (i < N_NODES) ? deg[i] : 0;
#pragma unroll
  for (int off = 32; off; off >>= 1) v += __shfl_xor(v, off);
  __shared__ int wsum[16];
  if ((threadIdx.x & 63) == 0) wsum[threadIdx.x >> 6] = v;
  __syncthreads();
  if (threadIdx.x == 0) {
    int s = 0;
#pragma unroll
    for (int w = 0; w < 16; ++w) s += wsum[w];
    blockSums[blockIdx.x] = s;
  }
}

__global__ void scan_p2(const int* __restrict__ blockSums, int* __restrict__ blockOffs) {
  if (threadIdx.x == 0) {
    int s = 0;
    for (int b = 0; b < SCAN_NB; ++b) { blockOffs[b] = s; s += blockSums[b]; }
  }
}

__global__ __launch_bounds__(1024) void scan_p3(const int* __restrict__ deg,
                                                const int* __restrict__ blockOffs,
                                                int* __restrict__ rowptr,
                                                int* __restrict__ fillpos) {
  __shared__ int sh[1024];
  int i = blockIdx.x * 1024 + threadIdx.x;
  int v = (i < N_NODES) ? deg[i] : 0;
  sh[threadIdx.x] = v;
  __syncthreads();
  for (int off = 1; off < 1024; off <<= 1) {
    int t = (threadIdx.x >= off) ? sh[threadIdx.x - off] : 0;
    __syncthreads();
    sh[threadIdx.x] += t;
    __syncthreads();
  }
  if (i < N_NODES) {
    int excl = sh[threadIdx.x] - v + blockOffs[blockIdx.x];
    rowptr[i] = excl;
    fillpos[i] = excl;
    if (i == N_NODES - 1) rowptr[N_NODES] = excl + v;
  }
}

__global__ void fill_kernel(const int* __restrict__ ei, int* __restrict__ fillpos,
                            int* __restrict__ col) {
  int e = blockIdx.x * 256 + threadIdx.x;
  if (e >= E_TOT) return;
  int s, d;
  if (e < N_EDGES) { s = ei[e]; d = ei[N_EDGES + e]; }
  else { s = d = e - N_EDGES; }
  int p = atomicAdd(&fillpos[d], 1);
  col[p] = s;
}

// ---------------- weight transpose + bf16 cast (tiny) ----------------

__global__ void transpose_cast(const float* __restrict__ W, ushort_t* __restrict__ Wt,
                               int K, int Nc) {
  int i = blockIdx.x * 256 + threadIdx.x;
  if (i >= K * Nc) return;
  int n = i / K, k = i - n * K;
  Wt[i] = f2b(W[(size_t)k * Nc + n]);   // Wt[n][k] = W[k][n]
}

// ---------------- MFMA GEMM: Out[M][NTOT](bf16) = A[M][KTOT] @ Bt^T ----------------
// Block: 128 rows x (WAVES_N*64) cols, 4 waves. A staged in LDS (XOR-swizzled),
// B fragments held in registers from transposed weights (L2-resident).

template <int WAVES_M, int WAVES_N, int KTOT, bool A_FP32>
__global__ __launch_bounds__(256) void mfma_gemm(
    const void* __restrict__ Aptr, const ushort_t* __restrict__ Bt,
    ushort_t* __restrict__ Out, int M, int NTOT) {
  constexpr int BM = 128;
  constexpr int WN = 64;
  constexpr int WM = BM / WAVES_M;
  constexpr int M_REP = WM / 16;
  constexpr int N_REP = WN / 16;
  constexpr int KC = 128;
  __shared__ ushort_t As[BM * KC];

  const int tid = threadIdx.x;
  const int lane = tid & 63;
  const int wid = tid >> 6;
  const int wm = wid % WAVES_M;
  const int wn = wid / WAVES_M;
  const int rowBase = blockIdx.x * BM;
  const int colBase = blockIdx.y * (WAVES_N * WN) + wn * WN;
  const int l15 = lane & 15;
  const int l4 = lane >> 4;

  f32x4 acc[M_REP][N_REP] = {};

  for (int kc = 0; kc < KTOT; kc += KC) {
    if (kc) __syncthreads();
    // stage A[rowBase..+127][kc..kc+127] -> As (bf16, swizzled), zero-pad OOB rows
    for (int c = tid; c < BM * KC / 8; c += 256) {
      int r = c >> 4;
      int k8 = (c & 15) << 3;
      int gr = rowBase + r;
      short8v u = {};
      if (gr < M) {
        if (A_FP32) {
          const float* A = (const float*)Aptr;
          float4 f0 = *(const float4*)&A[(size_t)gr * KTOT + kc + k8];
          float4 f1 = *(const float4*)&A[(size_t)gr * KTOT + kc + k8 + 4];
          u[0] = (short)f2b(f0.x); u[1] = (short)f2b(f0.y);
          u[2] = (short)f2b(f0.z); u[3] = (short)f2b(f0.w);
          u[4] = (short)f2b(f1.x); u[5] = (short)f2b(f1.y);
          u[6] = (short)f2b(f1.z); u[7] = (short)f2b(f1.w);
        } else {
          const ushort_t* A = (const ushort_t*)Aptr;
          u = *(const short8v*)&A[(size_t)gr * KTOT + kc + k8];
        }
      }
      int byte = (r * KC + k8) * 2;
      byte ^= (r & 7) << 4;  // G4 swizzle: breaks row-stride bank conflict
      *(short8v*)((char*)As + byte) = u;
    }
    // B fragments: col = l&15 of Bt row, 8 contiguous k per lane
    short8v bfr[KC / 32][N_REP];
#pragma unroll
    for (int kk = 0; kk < KC / 32; ++kk)
#pragma unroll
      for (int n = 0; n < N_REP; ++n) {
        int bcol = colBase + n * 16 + l15;
        int k0 = kc + kk * 32 + l4 * 8;
        bfr[kk][n] = *(const short8v*)&Bt[(size_t)bcol * KTOT + k0];
      }
    __syncthreads();
#pragma unroll
    for (int kk = 0; kk < KC / 32; ++kk) {
      short8v afr[M_REP];
#pragma unroll
      for (int m = 0; m < M_REP; ++m) {
        int r = wm * WM + m * 16 + l15;
        int k0 = kk * 32 + l4 * 8;
        int byte = ((r * KC + k0) * 2) ^ ((r & 7) << 4);
        afr[m] = *(const short8v*)((const char*)As + byte);
      }
#pragma unroll
      for (int m = 0; m < M_REP; ++m)
#pragma unroll
        for (int n = 0; n < N_REP; ++n)
          acc[m][n] = __builtin_amdgcn_mfma_f32_16x16x32_bf16(
              afr[m], bfr[kk][n], acc[m][n], 0, 0, 0);
    }
  }
  // epilogue: C/D layout col=lane&15, row=(lane>>4)*4+reg
#pragma unroll
  for (int m = 0; m < M_REP; ++m) {
    int r0 = rowBase + wm * WM + m * 16 + l4 * 4;
#pragma unroll
    for (int n = 0; n < N_REP; ++n) {
      int gc = colBase + n * 16 + l15;
#pragma unroll
      for (int j = 0; j < 4; ++j) {
        int gr = r0 + j;
        if (gr < M) Out[(size_t)gr * NTOT + gc] = f2b(acc[m][n][j]);
      }
    }
  }
}

// ---------------- per-node attention scalars (bf16 h) ----------------

template <int C>
__global__ __launch_bounds__(256) void alpha_kernel(
    const ushort_t* __restrict__ h, const float* __restrict__ vs,
    const float* __restrict__ vd, float* __restrict__ os, float* __restrict__ od) {
  int n = blockIdx.x * 4 + (threadIdx.x >> 6);
  if (n >= N_NODES) return;
  int lane = threadIdx.x & 63;
  float ps = 0.f, pd = 0.f;
  if (C == 256) {
    ushort4 u = *reinterpret_cast<const ushort4*>(&h[(size_t)n * 256 + lane * 4]);
    float f0 = b2f(u.x), f1 = b2f(u.y), f2 = b2f(u.z), f3 = b2f(u.w);
    ps = f0 * vs[lane * 4] + f1 * vs[lane * 4 + 1] + f2 * vs[lane * 4 + 2] + f3 * vs[lane * 4 + 3];
    pd = f0 * vd[lane * 4] + f1 * vd[lane * 4 + 1] + f2 * vd[lane * 4 + 2] + f3 * vd[lane * 4 + 3];
  } else {
    float f = b2f(h[(size_t)n * 64 + lane]);
    ps = f * vs[lane];
    pd = f * vd[lane];
  }
#pragma unroll
  for (int off = 32; off; off >>= 1) {
    ps += __shfl_xor(ps, off);
    pd += __shfl_xor(pd, off);
  }
  if (lane == 0) { os[n] = ps; od[n] = pd; }
}

// per-node softmax over incoming edges; writes normalized alpha per edge
__global__ __launch_bounds__(256) void softmax_prep(
    const int* __restrict__ rowptr, const int* __restrict__ col,
    const float* __restrict__ asrc, const float* __restrict__ adst,
    float* __restrict__ alphaE) {
  int n = blockIdx.x * 4 + (threadIdx.x >> 6);
  if (n >= N_NODES) return;
  int lane = threadIdx.x & 63;
  int beg = rowptr[n], end = rowptr[n + 1];
  float ad = adst[n];
  float m = -1e30f;
  for (int j = beg + lane; j < end; j += 64)
    m = fmaxf(m, leaky(asrc[col[j]] + ad));
#pragma unroll
  for (int off = 32; off; off >>= 1) m = fmaxf(m, __shfl_xor(m, off));
  float ssum = 0.f;
  for (int j = beg + lane; j < end; j += 64)
    ssum += expf(leaky(asrc[col[j]] + ad) - m);
#pragma unroll
  for (int off = 32; off; off >>= 1) ssum += __shfl_xor(ssum, off);
  float inv = 1.0f / ssum;
  for (int j = beg + lane; j < end; j += 64)
    alphaE[j] = expf(leaky(asrc[col[j]] + ad) - m) * inv;
}

// ---------------- aggregation (bf16 h gathers, fp32 accum) ----------------

// layer 1: wave per node, lane = 4 channels; fused relu(acc + b1) -> bf16 out
__global__ __launch_bounds__(256) void aggregate1(
    const ushort_t* __restrict__ h, const int* __restrict__ rowptr,
    const int* __restrict__ col, const float* __restrict__ alphaE,
    const float* __restrict__ bias, ushort_t* __restrict__ out) {
  int n = blockIdx.x * 4 + (threadIdx.x >> 6);
  if (n >= N_NODES) return;
  int lane = threadIdx.x & 63;
  int beg = rowptr[n], end = rowptr[n + 1];
  float a0 = 0.f, a1 = 0.f, a2 = 0.f, a3 = 0.f;
  for (int j = beg; j < end; ++j) {
    int s = col[j];
    float al = alphaE[j];
    ushort4 u = *reinterpret_cast<const ushort4*>(&h[(size_t)s * 256 + lane * 4]);
    a0 += al * b2f(u.x);
    a1 += al * b2f(u.y);
    a2 += al * b2f(u.z);
    a3 += al * b2f(u.w);
  }
  float4 bv = *reinterpret_cast<const float4*>(&bias[lane * 4]);
  ushort4 o;
  o.x = f2b(fmaxf(a0 + bv.x, 0.f));
  o.y = f2b(fmaxf(a1 + bv.y, 0.f));
  o.z = f2b(fmaxf(a2 + bv.z, 0.f));
  o.w = f2b(fmaxf(a3 + bv.w, 0.f));
  *reinterpret_cast<ushort4*>(&out[(size_t)n * 256 + lane * 4]) = o;
}

// layer 2: wave per node (C=64), bf16 gathers, fused +bias, final output
__global__ __launch_bounds__(256) void aggregate2(
    const ushort_t* __restrict__ h, const int* __restrict__ rowptr,
    const int* __restrict__ col, const float* __restrict__ alphaE,
    const float* __restrict__ bias, float* __restrict__ out) {
  int n = blockIdx.x * 4 + (threadIdx.x >> 6);
  if (n >= N_NODES) return;
  int lane = threadIdx.x & 63;
  int beg = rowptr[n], end = rowptr[n + 1];
  float acc = 0.f;
  for (int j = beg; j < end; ++j)
    acc += alphaE[j] * b2f(h[(size_t)col[j] * 64 + lane]);
  out[(size_t)n * 64 + lane] = acc + bias[lane];
}

// ---------------- launch ----------------

extern "C" void kernel_launch(void* const* d_in, const int* in_sizes, int n_in,
                              void* d_out, int out_size, void* d_ws, size_t ws_size,
                              hipStream_t stream) {
  const float* x    = (const float*)d_in[0];
  const int*   ei   = (const int*)d_in[1];
  const float* W1   = (const float*)d_in[2];
  const float* a1s  = (const float*)d_in[3];
  const float* a1d  = (const float*)d_in[4];
  const float* b1   = (const float*)d_in[5];
  const float* W2   = (const float*)d_in[6];
  const float* a2s  = (const float*)d_in[7];
  const float* a2d  = (const float*)d_in[8];
  const float* b2   = (const float*)d_in[9];
  float* out = (float*)d_out;

  char* ws = (char*)d_ws;
  size_t off = 0;
  auto alloc = [&](size_t bytes) {
    void* p = ws + off;
    off += bytes;
    off = (off + 255) & ~(size_t)255;
    return p;
  };

  ushort_t* h1   = (ushort_t*)alloc((size_t)N_NODES * 256 * 2);  // bf16
  ushort_t* a1b  = (ushort_t*)alloc((size_t)N_NODES * 256 * 2);  // bf16 relu(agg1+b1)
  ushort_t* h2   = (ushort_t*)alloc((size_t)N_NODES * 64 * 2);   // bf16
  ushort_t* W1t  = (ushort_t*)alloc((size_t)256 * 128 * 2);
  ushort_t* W2t  = (ushort_t*)alloc((size_t)64 * 256 * 2);
  float* asrc1   = (float*)alloc((size_t)N_NODES * 4);
  float* adst1   = (float*)alloc((size_t)N_NODES * 4);
  float* asrc2   = (float*)alloc((size_t)N_NODES * 4);
  float* adst2   = (float*)alloc((size_t)N_NODES * 4);
  float* alphaE  = (float*)alloc((size_t)E_TOT * 4);
  int*   deg     = (int*)alloc((size_t)N_NODES * 4);
  int*   rowptr  = (int*)alloc((size_t)(N_NODES + 1) * 4);
  int*   fillp   = (int*)alloc((size_t)N_NODES * 4);
  int*   col     = (int*)alloc((size_t)E_TOT * 4);
  int*   bsums   = (int*)alloc((size_t)SCAN_NB * 4);
  int*   boffs   = (int*)alloc((size_t)SCAN_NB * 4);

  const int edgeBlocks = (E_TOT + 255) / 256;
  const int nodeBlocks4 = (N_NODES + 3) / 4;
  const int gemmBlocksM = (N_NODES + 127) / 128;

  // CSR build
  hipMemsetAsync(deg, 0, (size_t)N_NODES * 4, stream);
  degree_kernel<<<edgeBlocks, 256, 0, stream>>>(ei, deg);
  scan_p1<<<SCAN_NB, 1024, 0, stream>>>(deg, bsums);
  scan_p2<<<1, 64, 0, stream>>>(bsums, boffs);
  scan_p3<<<SCAN_NB, 1024, 0, stream>>>(deg, boffs, rowptr, fillp);
  fill_kernel<<<edgeBlocks, 256, 0, stream>>>(ei, fillp, col);

  // weight prep
  transpose_cast<<<(256 * 128 + 255) / 256, 256, 0, stream>>>(W1, W1t, 128, 256);
  transpose_cast<<<(64 * 256 + 255) / 256, 256, 0, stream>>>(W2, W2t, 256, 64);

  // layer 1: h1 = bf16(x) @ bf16(W1)   (fp32 x cast fused in staging)
  mfma_gemm<2, 2, 128, true><<<dim3(gemmBlocksM, 2), 256, 0, stream>>>(
      x, W1t, h1, N_NODES, 256);
  alpha_kernel<256><<<nodeBlocks4, 256, 0, stream>>>(h1, a1s, a1d, asrc1, adst1);
  softmax_prep<<<nodeBlocks4, 256, 0, stream>>>(rowptr, col, asrc1, adst1, alphaE);
  aggregate1<<<nodeBlocks4, 256, 0, stream>>>(h1, rowptr, col, alphaE, b1, a1b);

  // layer 2: h2 = a1b @ bf16(W2)
  mfma_gemm<4, 1, 256, false><<<dim3(gemmBlocksM, 1), 256, 0, stream>>>(
      a1b, W2t, h2, N_NODES, 64);
  alpha_kernel<64><<<nodeBlocks4, 256, 0, stream>>>(h2, a2s, a2d, asrc2, adst2);
  softmax_prep<<<nodeBlocks4, 256, 0, stream>>>(rowptr, col, asrc2, adst2, alphaE);
  aggregate2<<<nodeBlocks4, 256, 0, stream>>>(h2, rowptr, col, alphaE, b2, out);
}

// Round 5
// 395.630 us; speedup vs baseline: 2.3142x; 1.1998x over previous
//
#include <hip/hip_runtime.h>
#include <math.h>

#define N_NODES 100000
#define N_EDGES 800000
#define E_TOT (N_EDGES + N_NODES)
#define NEG_SLOPE 0.2f
#define SCAN_NB ((N_NODES + 1023) / 1024)

typedef unsigned short ushort_t;
typedef __attribute__((ext_vector_type(8))) short short8v;   // 8 bf16
typedef __attribute__((ext_vector_type(4))) float f32x4;

static __device__ __forceinline__ float leaky(float e) {
  return e > 0.f ? e : NEG_SLOPE * e;
}

static __device__ __forceinline__ float b2f(ushort_t u) {
  union { unsigned int i; float f; } x;
  x.i = ((unsigned int)u) << 16;
  return x.f;
}

static __device__ __forceinline__ ushort_t f2b(float f) {
  union { float f; unsigned int i; } x;
  x.f = f;
  unsigned int r = x.i + 0x7FFFu + ((x.i >> 16) & 1u);  // RNE (finite inputs)
  return (ushort_t)(r >> 16);
}

// ---------------- CSR build ----------------

__global__ void degree_kernel(const int* __restrict__ ei, int* __restrict__ deg) {
  int e = blockIdx.x * 256 + threadIdx.x;
  if (e >= E_TOT) return;
  int d = (e < N_EDGES) ? ei[N_EDGES + e] : (e - N_EDGES);
  atomicAdd(&deg[d], 1);
}

__global__ __launch_bounds__(1024) void scan_p1(const int* __restrict__ deg,
                                                int* __restrict__ blockSums) {
  int i = blockIdx.x * 1024 + threadIdx.x;
  int v = (i < N_NODES) ? deg[i] : 0;
#pragma unroll
  for (int off = 32; off; off >>= 1) v += __shfl_xor(v, off);
  __shared__ int wsum[16];
  if ((threadIdx.x & 63) == 0) wsum[threadIdx.x >> 6] = v;
  __syncthreads();
  if (threadIdx.x == 0) {
    int s = 0;
#pragma unroll
    for (int w = 0; w < 16; ++w) s += wsum[w];
    blockSums[blockIdx.x] = s;
  }
}

__global__ void scan_p2(const int* __restrict__ blockSums, int* __restrict__ blockOffs) {
  if (threadIdx.x == 0) {
    int s = 0;
    for (int b = 0; b < SCAN_NB; ++b) { blockOffs[b] = s; s += blockSums[b]; }
  }
}

__global__ __launch_bounds__(1024) void scan_p3(const int* __restrict__ deg,
                                                const int* __restrict__ blockOffs,
                                                int* __restrict__ rowptr,
                                                int* __restrict__ fillpos) {
  __shared__ int sh[1024];
  int i = blockIdx.x * 1024 + threadIdx.x;
  int v = (i < N_NODES) ? deg[i] : 0;
  sh[threadIdx.x] = v;
  __syncthreads();
  for (int off = 1; off < 1024; off <<= 1) {
    int t = (threadIdx.x >= off) ? sh[threadIdx.x - off] : 0;
    __syncthreads();
    sh[threadIdx.x] += t;
    __syncthreads();
  }
  if (i < N_NODES) {
    int excl = sh[threadIdx.x] - v + blockOffs[blockIdx.x];
    rowptr[i] = excl;
    fillpos[i] = excl;
    if (i == N_NODES - 1) rowptr[N_NODES] = excl + v;
  }
}

__global__ void fill_kernel(const int* __restrict__ ei, int* __restrict__ fillpos,
                            int* __restrict__ col) {
  int e = blockIdx.x * 256 + threadIdx.x;
  if (e >= E_TOT) return;
  int s, d;
  if (e < N_EDGES) { s = ei[e]; d = ei[N_EDGES + e]; }
  else { s = d = e - N_EDGES; }
  int p = atomicAdd(&fillpos[d], 1);
  col[p] = s;
}

// ---------------- weight transpose + bf16 cast (tiny) ----------------

__global__ void transpose_cast(const float* __restrict__ W, ushort_t* __restrict__ Wt,
                               int K, int Nc) {
  int i = blockIdx.x * 256 + threadIdx.x;
  if (i >= K * Nc) return;
  int n = i / K, k = i - n * K;
  Wt[i] = f2b(W[(size_t)k * Nc + n]);   // Wt[n][k] = W[k][n]
}

// ---------------- MFMA GEMM: Out[M][NTOT](bf16) = A[M][KTOT] @ Bt^T ----------------

template <int WAVES_M, int WAVES_N, int KTOT, bool A_FP32>
__global__ __launch_bounds__(256) void mfma_gemm(
    const void* __restrict__ Aptr, const ushort_t* __restrict__ Bt,
    ushort_t* __restrict__ Out, int M, int NTOT) {
  constexpr int BM = 128;
  constexpr int WN = 64;
  constexpr int WM = BM / WAVES_M;
  constexpr int M_REP = WM / 16;
  constexpr int N_REP = WN / 16;
  constexpr int KC = 128;
  __shared__ ushort_t As[BM * KC];

  const int tid = threadIdx.x;
  const int lane = tid & 63;
  const int wid = tid >> 6;
  const int wm = wid % WAVES_M;
  const int wn = wid / WAVES_M;
  const int rowBase = blockIdx.x * BM;
  const int colBase = blockIdx.y * (WAVES_N * WN) + wn * WN;
  const int l15 = lane & 15;
  const int l4 = lane >> 4;

  f32x4 acc[M_REP][N_REP] = {};

  for (int kc = 0; kc < KTOT; kc += KC) {
    if (kc) __syncthreads();
    for (int c = tid; c < BM * KC / 8; c += 256) {
      int r = c >> 4;
      int k8 = (c & 15) << 3;
      int gr = rowBase + r;
      short8v u = {};
      if (gr < M) {
        if (A_FP32) {
          const float* A = (const float*)Aptr;
          float4 f0 = *(const float4*)&A[(size_t)gr * KTOT + kc + k8];
          float4 f1 = *(const float4*)&A[(size_t)gr * KTOT + kc + k8 + 4];
          u[0] = (short)f2b(f0.x); u[1] = (short)f2b(f0.y);
          u[2] = (short)f2b(f0.z); u[3] = (short)f2b(f0.w);
          u[4] = (short)f2b(f1.x); u[5] = (short)f2b(f1.y);
          u[6] = (short)f2b(f1.z); u[7] = (short)f2b(f1.w);
        } else {
          const ushort_t* A = (const ushort_t*)Aptr;
          u = *(const short8v*)&A[(size_t)gr * KTOT + kc + k8];
        }
      }
      int byte = (r * KC + k8) * 2;
      byte ^= (r & 7) << 4;  // G4 swizzle
      *(short8v*)((char*)As + byte) = u;
    }
    short8v bfr[KC / 32][N_REP];
#pragma unroll
    for (int kk = 0; kk < KC / 32; ++kk)
#pragma unroll
      for (int n = 0; n < N_REP; ++n) {
        int bcol = colBase + n * 16 + l15;
        int k0 = kc + kk * 32 + l4 * 8;
        bfr[kk][n] = *(const short8v*)&Bt[(size_t)bcol * KTOT + k0];
      }
    __syncthreads();
#pragma unroll
    for (int kk = 0; kk < KC / 32; ++kk) {
      short8v afr[M_REP];
#pragma unroll
      for (int m = 0; m < M_REP; ++m) {
        int r = wm * WM + m * 16 + l15;
        int k0 = kk * 32 + l4 * 8;
        int byte = ((r * KC + k0) * 2) ^ ((r & 7) << 4);
        afr[m] = *(const short8v*)((const char*)As + byte);
      }
#pragma unroll
      for (int m = 0; m < M_REP; ++m)
#pragma unroll
        for (int n = 0; n < N_REP; ++n)
          acc[m][n] = __builtin_amdgcn_mfma_f32_16x16x32_bf16(
              afr[m], bfr[kk][n], acc[m][n], 0, 0, 0);
    }
  }
#pragma unroll
  for (int m = 0; m < M_REP; ++m) {
    int r0 = rowBase + wm * WM + m * 16 + l4 * 4;
#pragma unroll
    for (int n = 0; n < N_REP; ++n) {
      int gc = colBase + n * 16 + l15;
#pragma unroll
      for (int j = 0; j < 4; ++j) {
        int gr = r0 + j;
        if (gr < M) Out[(size_t)gr * NTOT + gc] = f2b(acc[m][n][j]);
      }
    }
  }
}

// ---------------- per-node attention scalars (bf16 h) ----------------

template <int C>
__global__ __launch_bounds__(256) void alpha_kernel(
    const ushort_t* __restrict__ h, const float* __restrict__ vs,
    const float* __restrict__ vd, float* __restrict__ os, float* __restrict__ od) {
  int n = blockIdx.x * 4 + (threadIdx.x >> 6);
  if (n >= N_NODES) return;
  int lane = threadIdx.x & 63;
  float ps = 0.f, pd = 0.f;
  if (C == 256) {
    ushort4 u = *reinterpret_cast<const ushort4*>(&h[(size_t)n * 256 + lane * 4]);
    float f0 = b2f(u.x), f1 = b2f(u.y), f2 = b2f(u.z), f3 = b2f(u.w);
    ps = f0 * vs[lane * 4] + f1 * vs[lane * 4 + 1] + f2 * vs[lane * 4 + 2] + f3 * vs[lane * 4 + 3];
    pd = f0 * vd[lane * 4] + f1 * vd[lane * 4 + 1] + f2 * vd[lane * 4 + 2] + f3 * vd[lane * 4 + 3];
  } else {
    float f = b2f(h[(size_t)n * 64 + lane]);
    ps = f * vs[lane];
    pd = f * vd[lane];
  }
#pragma unroll
  for (int off = 32; off; off >>= 1) {
    ps += __shfl_xor(ps, off);
    pd += __shfl_xor(pd, off);
  }
  if (lane == 0) { os[n] = ps; od[n] = pd; }
}

// per-node softmax over incoming edges; writes normalized alpha per edge
__global__ __launch_bounds__(256) void softmax_prep(
    const int* __restrict__ rowptr, const int* __restrict__ col,
    const float* __restrict__ asrc, const float* __restrict__ adst,
    float* __restrict__ alphaE) {
  int n = blockIdx.x * 4 + (threadIdx.x >> 6);
  if (n >= N_NODES) return;
  int lane = threadIdx.x & 63;
  int beg = rowptr[n], end = rowptr[n + 1];
  float ad = adst[n];
  float m = -1e30f;
  for (int j = beg + lane; j < end; j += 64)
    m = fmaxf(m, leaky(asrc[col[j]] + ad));
#pragma unroll
  for (int off = 32; off; off >>= 1) m = fmaxf(m, __shfl_xor(m, off));
  float ssum = 0.f;
  for (int j = beg + lane; j < end; j += 64)
    ssum += expf(leaky(asrc[col[j]] + ad) - m);
#pragma unroll
  for (int off = 32; off; off >>= 1) ssum += __shfl_xor(ssum, off);
  float inv = 1.0f / ssum;
  for (int j = beg + lane; j < end; j += 64)
    alphaE[j] = expf(leaky(asrc[col[j]] + ad) - m) * inv;
}

// ---------------- aggregation (bf16 gathers, fp32 accum, 4x unrolled ILP) ----------------

// layer 1: wave per node, lane = 4 channels; 4 independent gathers in flight;
// fused relu(acc + b1) -> bf16 out
__global__ __launch_bounds__(256) void aggregate1(
    const ushort_t* __restrict__ h, const int* __restrict__ rowptr,
    const int* __restrict__ col, const float* __restrict__ alphaE,
    const float* __restrict__ bias, ushort_t* __restrict__ out) {
  int n = blockIdx.x * 4 + (threadIdx.x >> 6);
  if (n >= N_NODES) return;
  int lane = threadIdx.x & 63;
  int beg = rowptr[n], end = rowptr[n + 1];
  float a0 = 0.f, a1 = 0.f, a2 = 0.f, a3 = 0.f;
  int j = beg;
  for (; j + 4 <= end; j += 4) {
    int s0 = col[j], s1 = col[j + 1], s2 = col[j + 2], s3 = col[j + 3];
    float al0 = alphaE[j], al1 = alphaE[j + 1], al2 = alphaE[j + 2], al3 = alphaE[j + 3];
    ushort4 u0 = *reinterpret_cast<const ushort4*>(&h[(size_t)s0 * 256 + lane * 4]);
    ushort4 u1 = *reinterpret_cast<const ushort4*>(&h[(size_t)s1 * 256 + lane * 4]);
    ushort4 u2 = *reinterpret_cast<const ushort4*>(&h[(size_t)s2 * 256 + lane * 4]);
    ushort4 u3 = *reinterpret_cast<const ushort4*>(&h[(size_t)s3 * 256 + lane * 4]);
    a0 += al0 * b2f(u0.x) + al1 * b2f(u1.x) + al2 * b2f(u2.x) + al3 * b2f(u3.x);
    a1 += al0 * b2f(u0.y) + al1 * b2f(u1.y) + al2 * b2f(u2.y) + al3 * b2f(u3.y);
    a2 += al0 * b2f(u0.z) + al1 * b2f(u1.z) + al2 * b2f(u2.z) + al3 * b2f(u3.z);
    a3 += al0 * b2f(u0.w) + al1 * b2f(u1.w) + al2 * b2f(u2.w) + al3 * b2f(u3.w);
  }
  for (; j < end; ++j) {
    int s = col[j];
    float al = alphaE[j];
    ushort4 u = *reinterpret_cast<const ushort4*>(&h[(size_t)s * 256 + lane * 4]);
    a0 += al * b2f(u.x);
    a1 += al * b2f(u.y);
    a2 += al * b2f(u.z);
    a3 += al * b2f(u.w);
  }
  float4 bv = *reinterpret_cast<const float4*>(&bias[lane * 4]);
  ushort4 o;
  o.x = f2b(fmaxf(a0 + bv.x, 0.f));
  o.y = f2b(fmaxf(a1 + bv.y, 0.f));
  o.z = f2b(fmaxf(a2 + bv.z, 0.f));
  o.w = f2b(fmaxf(a3 + bv.w, 0.f));
  *reinterpret_cast<ushort4*>(&out[(size_t)n * 256 + lane * 4]) = o;
}

// layer 2: wave per node (C=64), 4x unrolled bf16 gathers, fused +bias, final output
__global__ __launch_bounds__(256) void aggregate2(
    const ushort_t* __restrict__ h, const int* __restrict__ rowptr,
    const int* __restrict__ col, const float* __restrict__ alphaE,
    const float* __restrict__ bias, float* __restrict__ out) {
  int n = blockIdx.x * 4 + (threadIdx.x >> 6);
  if (n >= N_NODES) return;
  int lane = threadIdx.x & 63;
  int beg = rowptr[n], end = rowptr[n + 1];
  float acc = 0.f;
  int j = beg;
  for (; j + 4 <= end; j += 4) {
    int s0 = col[j], s1 = col[j + 1], s2 = col[j + 2], s3 = col[j + 3];
    float al0 = alphaE[j], al1 = alphaE[j + 1], al2 = alphaE[j + 2], al3 = alphaE[j + 3];
    ushort_t u0 = h[(size_t)s0 * 64 + lane];
    ushort_t u1 = h[(size_t)s1 * 64 + lane];
    ushort_t u2 = h[(size_t)s2 * 64 + lane];
    ushort_t u3 = h[(size_t)s3 * 64 + lane];
    acc += al0 * b2f(u0) + al1 * b2f(u1) + al2 * b2f(u2) + al3 * b2f(u3);
  }
  for (; j < end; ++j)
    acc += alphaE[j] * b2f(h[(size_t)col[j] * 64 + lane]);
  out[(size_t)n * 64 + lane] = acc + bias[lane];
}

// ---------------- launch ----------------

extern "C" void kernel_launch(void* const* d_in, const int* in_sizes, int n_in,
                              void* d_out, int out_size, void* d_ws, size_t ws_size,
                              hipStream_t stream) {
  const float* x    = (const float*)d_in[0];
  const int*   ei   = (const int*)d_in[1];
  const float* W1   = (const float*)d_in[2];
  const float* a1s  = (const float*)d_in[3];
  const float* a1d  = (const float*)d_in[4];
  const float* b1   = (const float*)d_in[5];
  const float* W2   = (const float*)d_in[6];
  const float* a2s  = (const float*)d_in[7];
  const float* a2d  = (const float*)d_in[8];
  const float* b2   = (const float*)d_in[9];
  float* out = (float*)d_out;

  char* ws = (char*)d_ws;
  size_t off = 0;
  auto alloc = [&](size_t bytes) {
    void* p = ws + off;
    off += bytes;
    off = (off + 255) & ~(size_t)255;
    return p;
  };

  ushort_t* h1   = (ushort_t*)alloc((size_t)N_NODES * 256 * 2);  // bf16
  ushort_t* a1b  = (ushort_t*)alloc((size_t)N_NODES * 256 * 2);  // bf16 relu(agg1+b1)
  ushort_t* h2   = (ushort_t*)alloc((size_t)N_NODES * 64 * 2);   // bf16
  ushort_t* W1t  = (ushort_t*)alloc((size_t)256 * 128 * 2);
  ushort_t* W2t  = (ushort_t*)alloc((size_t)64 * 256 * 2);
  float* asrc1   = (float*)alloc((size_t)N_NODES * 4);
  float* adst1   = (float*)alloc((size_t)N_NODES * 4);
  float* asrc2   = (float*)alloc((size_t)N_NODES * 4);
  float* adst2   = (float*)alloc((size_t)N_NODES * 4);
  float* alphaE  = (float*)alloc((size_t)E_TOT * 4);
  int*   deg     = (int*)alloc((size_t)N_NODES * 4);
  int*   rowptr  = (int*)alloc((size_t)(N_NODES + 1) * 4);
  int*   fillp   = (int*)alloc((size_t)N_NODES * 4);
  int*   col     = (int*)alloc((size_t)E_TOT * 4);
  int*   bsums   = (int*)alloc((size_t)SCAN_NB * 4);
  int*   boffs   = (int*)alloc((size_t)SCAN_NB * 4);

  const int edgeBlocks = (E_TOT + 255) / 256;
  const int nodeBlocks4 = (N_NODES + 3) / 4;
  const int gemmBlocksM = (N_NODES + 127) / 128;

  // CSR build
  hipMemsetAsync(deg, 0, (size_t)N_NODES * 4, stream);
  degree_kernel<<<edgeBlocks, 256, 0, stream>>>(ei, deg);
  scan_p1<<<SCAN_NB, 1024, 0, stream>>>(deg, bsums);
  scan_p2<<<1, 64, 0, stream>>>(bsums, boffs);
  scan_p3<<<SCAN_NB, 1024, 0, stream>>>(deg, boffs, rowptr, fillp);
  fill_kernel<<<edgeBlocks, 256, 0, stream>>>(ei, fillp, col);

  // weight prep
  transpose_cast<<<(256 * 128 + 255) / 256, 256, 0, stream>>>(W1, W1t, 128, 256);
  transpose_cast<<<(64 * 256 + 255) / 256, 256, 0, stream>>>(W2, W2t, 256, 64);

  // layer 1: h1 = bf16(x) @ bf16(W1)
  mfma_gemm<2, 2, 128, true><<<dim3(gemmBlocksM, 2), 256, 0, stream>>>(
      x, W1t, h1, N_NODES, 256);
  alpha_kernel<256><<<nodeBlocks4, 256, 0, stream>>>(h1, a1s, a1d, asrc1, adst1);
  softmax_prep<<<nodeBlocks4, 256, 0, stream>>>(rowptr, col, asrc1, adst1, alphaE);
  aggregate1<<<nodeBlocks4, 256, 0, stream>>>(h1, rowptr, col, alphaE, b1, a1b);

  // layer 2: h2 = a1b @ bf16(W2)
  mfma_gemm<4, 1, 256, false><<<dim3(gemmBlocksM, 1), 256, 0, stream>>>(
      a1b, W2t, h2, N_NODES, 64);
  alpha_kernel<64><<<nodeBlocks4, 256, 0, stream>>>(h2, a2s, a2d, asrc2, adst2);
  softmax_prep<<<nodeBlocks4, 256, 0, stream>>>(rowptr, col, asrc2, adst2, alphaE);
  aggregate2<<<nodeBlocks4, 256, 0, stream>>>(h2, rowptr, col, alphaE, b2, out);
}

// Round 6
// 356.268 us; speedup vs baseline: 2.5699x; 1.1105x over previous
//
#include <hip/hip_runtime.h>
#include <math.h>

#define N_NODES 100000
#define N_EDGES 800000
#define E_TOT (N_EDGES + N_NODES)
#define NEG_SLOPE 0.2f
#define SCAN_NB ((N_NODES + 1023) / 1024)

typedef unsigned short ushort_t;
typedef __attribute__((ext_vector_type(8))) short short8v;   // 8 bf16
typedef __attribute__((ext_vector_type(4))) float f32x4;

static __device__ __forceinline__ float leaky(float e) {
  return e > 0.f ? e : NEG_SLOPE * e;
}

static __device__ __forceinline__ float b2f(ushort_t u) {
  union { unsigned int i; float f; } x;
  x.i = ((unsigned int)u) << 16;
  return x.f;
}

static __device__ __forceinline__ ushort_t f2b(float f) {
  union { float f; unsigned int i; } x;
  x.f = f;
  unsigned int r = x.i + 0x7FFFu + ((x.i >> 16) & 1u);  // RNE (finite inputs)
  return (ushort_t)(r >> 16);
}

// ---------------- CSR build ----------------

__global__ void degree_kernel(const int* __restrict__ ei, int* __restrict__ deg) {
  int e = blockIdx.x * 256 + threadIdx.x;
  if (e >= E_TOT) return;
  int d = (e < N_EDGES) ? ei[N_EDGES + e] : (e - N_EDGES);
  atomicAdd(&deg[d], 1);
}

__global__ __launch_bounds__(1024) void scan_p1(const int* __restrict__ deg,
                                                int* __restrict__ blockSums) {
  int i = blockIdx.x * 1024 + threadIdx.x;
  int v = (i < N_NODES) ? deg[i] : 0;
#pragma unroll
  for (int off = 32; off; off >>= 1) v += __shfl_xor(v, off);
  __shared__ int wsum[16];
  if ((threadIdx.x & 63) == 0) wsum[threadIdx.x >> 6] = v;
  __syncthreads();
  if (threadIdx.x == 0) {
    int s = 0;
#pragma unroll
    for (int w = 0; w < 16; ++w) s += wsum[w];
    blockSums[blockIdx.x] = s;
  }
}

__global__ void scan_p2(const int* __restrict__ blockSums, int* __restrict__ blockOffs) {
  if (threadIdx.x == 0) {
    int s = 0;
    for (int b = 0; b < SCAN_NB; ++b) { blockOffs[b] = s; s += blockSums[b]; }
  }
}

__global__ __launch_bounds__(1024) void scan_p3(const int* __restrict__ deg,
                                                const int* __restrict__ blockOffs,
                                                int* __restrict__ rowptr,
                                                int* __restrict__ fillpos) {
  __shared__ int sh[1024];
  int i = blockIdx.x * 1024 + threadIdx.x;
  int v = (i < N_NODES) ? deg[i] : 0;
  sh[threadIdx.x] = v;
  __syncthreads();
  for (int off = 1; off < 1024; off <<= 1) {
    int t = (threadIdx.x >= off) ? sh[threadIdx.x - off] : 0;
    __syncthreads();
    sh[threadIdx.x] += t;
    __syncthreads();
  }
  if (i < N_NODES) {
    int excl = sh[threadIdx.x] - v + blockOffs[blockIdx.x];
    rowptr[i] = excl;
    fillpos[i] = excl;
    if (i == N_NODES - 1) rowptr[N_NODES] = excl + v;
  }
}

__global__ void fill_kernel(const int* __restrict__ ei, int* __restrict__ fillpos,
                            int* __restrict__ col) {
  int e = blockIdx.x * 256 + threadIdx.x;
  if (e >= E_TOT) return;
  int s, d;
  if (e < N_EDGES) { s = ei[e]; d = ei[N_EDGES + e]; }
  else { s = d = e - N_EDGES; }
  int p = atomicAdd(&fillpos[d], 1);
  col[p] = s;
}

// ---------------- weight transpose + bf16 cast (tiny) ----------------

__global__ void transpose_cast(const float* __restrict__ W, ushort_t* __restrict__ Wt,
                               int K, int Nc) {
  int i = blockIdx.x * 256 + threadIdx.x;
  if (i >= K * Nc) return;
  int n = i / K, k = i - n * K;
  Wt[i] = f2b(W[(size_t)k * Nc + n]);   // Wt[n][k] = W[k][n]
}

// ---------------- MFMA GEMM: Out[M][NTOT](bf16) = A[M][KTOT] @ Bt^T ----------------

template <int WAVES_M, int WAVES_N, int KTOT, bool A_FP32>
__global__ __launch_bounds__(256) void mfma_gemm(
    const void* __restrict__ Aptr, const ushort_t* __restrict__ Bt,
    ushort_t* __restrict__ Out, int M, int NTOT) {
  constexpr int BM = 128;
  constexpr int WN = 64;
  constexpr int WM = BM / WAVES_M;
  constexpr int M_REP = WM / 16;
  constexpr int N_REP = WN / 16;
  constexpr int KC = 128;
  __shared__ ushort_t As[BM * KC];

  const int tid = threadIdx.x;
  const int lane = tid & 63;
  const int wid = tid >> 6;
  const int wm = wid % WAVES_M;
  const int wn = wid / WAVES_M;
  const int rowBase = blockIdx.x * BM;
  const int colBase = blockIdx.y * (WAVES_N * WN) + wn * WN;
  const int l15 = lane & 15;
  const int l4 = lane >> 4;

  f32x4 acc[M_REP][N_REP] = {};

  for (int kc = 0; kc < KTOT; kc += KC) {
    if (kc) __syncthreads();
    for (int c = tid; c < BM * KC / 8; c += 256) {
      int r = c >> 4;
      int k8 = (c & 15) << 3;
      int gr = rowBase + r;
      short8v u = {};
      if (gr < M) {
        if (A_FP32) {
          const float* A = (const float*)Aptr;
          float4 f0 = *(const float4*)&A[(size_t)gr * KTOT + kc + k8];
          float4 f1 = *(const float4*)&A[(size_t)gr * KTOT + kc + k8 + 4];
          u[0] = (short)f2b(f0.x); u[1] = (short)f2b(f0.y);
          u[2] = (short)f2b(f0.z); u[3] = (short)f2b(f0.w);
          u[4] = (short)f2b(f1.x); u[5] = (short)f2b(f1.y);
          u[6] = (short)f2b(f1.z); u[7] = (short)f2b(f1.w);
        } else {
          const ushort_t* A = (const ushort_t*)Aptr;
          u = *(const short8v*)&A[(size_t)gr * KTOT + kc + k8];
        }
      }
      int byte = (r * KC + k8) * 2;
      byte ^= (r & 7) << 4;  // G4 swizzle
      *(short8v*)((char*)As + byte) = u;
    }
    short8v bfr[KC / 32][N_REP];
#pragma unroll
    for (int kk = 0; kk < KC / 32; ++kk)
#pragma unroll
      for (int n = 0; n < N_REP; ++n) {
        int bcol = colBase + n * 16 + l15;
        int k0 = kc + kk * 32 + l4 * 8;
        bfr[kk][n] = *(const short8v*)&Bt[(size_t)bcol * KTOT + k0];
      }
    __syncthreads();
#pragma unroll
    for (int kk = 0; kk < KC / 32; ++kk) {
      short8v afr[M_REP];
#pragma unroll
      for (int m = 0; m < M_REP; ++m) {
        int r = wm * WM + m * 16 + l15;
        int k0 = kk * 32 + l4 * 8;
        int byte = ((r * KC + k0) * 2) ^ ((r & 7) << 4);
        afr[m] = *(const short8v*)((const char*)As + byte);
      }
#pragma unroll
      for (int m = 0; m < M_REP; ++m)
#pragma unroll
        for (int n = 0; n < N_REP; ++n)
          acc[m][n] = __builtin_amdgcn_mfma_f32_16x16x32_bf16(
              afr[m], bfr[kk][n], acc[m][n], 0, 0, 0);
    }
  }
#pragma unroll
  for (int m = 0; m < M_REP; ++m) {
    int r0 = rowBase + wm * WM + m * 16 + l4 * 4;
#pragma unroll
    for (int n = 0; n < N_REP; ++n) {
      int gc = colBase + n * 16 + l15;
#pragma unroll
      for (int j = 0; j < 4; ++j) {
        int gr = r0 + j;
        if (gr < M) Out[(size_t)gr * NTOT + gc] = f2b(acc[m][n][j]);
      }
    }
  }
}

// ---------------- per-node attention scalars (bf16 h) ----------------

template <int C>
__global__ __launch_bounds__(256) void alpha_kernel(
    const ushort_t* __restrict__ h, const float* __restrict__ vs,
    const float* __restrict__ vd, float* __restrict__ os, float* __restrict__ od) {
  int n = blockIdx.x * 4 + (threadIdx.x >> 6);
  if (n >= N_NODES) return;
  int lane = threadIdx.x & 63;
  float ps = 0.f, pd = 0.f;
  if (C == 256) {
    ushort4 u = *reinterpret_cast<const ushort4*>(&h[(size_t)n * 256 + lane * 4]);
    float f0 = b2f(u.x), f1 = b2f(u.y), f2 = b2f(u.z), f3 = b2f(u.w);
    ps = f0 * vs[lane * 4] + f1 * vs[lane * 4 + 1] + f2 * vs[lane * 4 + 2] + f3 * vs[lane * 4 + 3];
    pd = f0 * vd[lane * 4] + f1 * vd[lane * 4 + 1] + f2 * vd[lane * 4 + 2] + f3 * vd[lane * 4 + 3];
  } else {
    float f = b2f(h[(size_t)n * 64 + lane]);
    ps = f * vs[lane];
    pd = f * vd[lane];
  }
#pragma unroll
  for (int off = 32; off; off >>= 1) {
    ps += __shfl_xor(ps, off);
    pd += __shfl_xor(pd, off);
  }
  if (lane == 0) { os[n] = ps; od[n] = pd; }
}

// ---------------- fused softmax + aggregation ----------------
// No-max softmax (e bounded; exp fits fp32). Pass A: lane l computes exp of
// edge l (deg<=64 in one round), wave-reduce denom. Pass B: 8 gathers in
// flight, weight broadcast via __shfl.

// layer 1: lane = 4 channels (C=256); fused relu(acc + b1) -> bf16 out
__global__ __launch_bounds__(256) void fused_agg1(
    const ushort_t* __restrict__ h, const int* __restrict__ rowptr,
    const int* __restrict__ col, const float* __restrict__ asrc,
    const float* __restrict__ adst, const float* __restrict__ bias,
    ushort_t* __restrict__ out) {
  int n = blockIdx.x * 4 + (threadIdx.x >> 6);
  if (n >= N_NODES) return;
  int lane = threadIdx.x & 63;
  int beg = rowptr[n], end = rowptr[n + 1];
  int deg = end - beg;
  float ad = adst[n];
  // pass A
  float we = 0.f;
  if (lane < deg) we = __expf(leaky(asrc[col[beg + lane]] + ad));
  float ssum = we;
  for (int jj = beg + 64 + lane; jj < end; jj += 64)   // essentially never
    ssum += __expf(leaky(asrc[col[jj]] + ad));
#pragma unroll
  for (int off = 32; off; off >>= 1) ssum += __shfl_xor(ssum, off);
  float inv = 1.0f / ssum;
  // pass B
  float a0 = 0.f, a1 = 0.f, a2 = 0.f, a3 = 0.f;
  if (deg <= 64) {
    int t = 0;
    for (; t + 8 <= deg; t += 8) {
      int s0 = col[beg + t],     s1 = col[beg + t + 1];
      int s2 = col[beg + t + 2], s3 = col[beg + t + 3];
      int s4 = col[beg + t + 4], s5 = col[beg + t + 5];
      int s6 = col[beg + t + 6], s7 = col[beg + t + 7];
      float w0 = __shfl(we, t) * inv,     w1 = __shfl(we, t + 1) * inv;
      float w2 = __shfl(we, t + 2) * inv, w3 = __shfl(we, t + 3) * inv;
      float w4 = __shfl(we, t + 4) * inv, w5 = __shfl(we, t + 5) * inv;
      float w6 = __shfl(we, t + 6) * inv, w7 = __shfl(we, t + 7) * inv;
      ushort4 u0 = *reinterpret_cast<const ushort4*>(&h[(size_t)s0 * 256 + lane * 4]);
      ushort4 u1 = *reinterpret_cast<const ushort4*>(&h[(size_t)s1 * 256 + lane * 4]);
      ushort4 u2 = *reinterpret_cast<const ushort4*>(&h[(size_t)s2 * 256 + lane * 4]);
      ushort4 u3 = *reinterpret_cast<const ushort4*>(&h[(size_t)s3 * 256 + lane * 4]);
      ushort4 u4 = *reinterpret_cast<const ushort4*>(&h[(size_t)s4 * 256 + lane * 4]);
      ushort4 u5 = *reinterpret_cast<const ushort4*>(&h[(size_t)s5 * 256 + lane * 4]);
      ushort4 u6 = *reinterpret_cast<const ushort4*>(&h[(size_t)s6 * 256 + lane * 4]);
      ushort4 u7 = *reinterpret_cast<const ushort4*>(&h[(size_t)s7 * 256 + lane * 4]);
      a0 += w0 * b2f(u0.x) + w1 * b2f(u1.x) + w2 * b2f(u2.x) + w3 * b2f(u3.x)
          + w4 * b2f(u4.x) + w5 * b2f(u5.x) + w6 * b2f(u6.x) + w7 * b2f(u7.x);
      a1 += w0 * b2f(u0.y) + w1 * b2f(u1.y) + w2 * b2f(u2.y) + w3 * b2f(u3.y)
          + w4 * b2f(u4.y) + w5 * b2f(u5.y) + w6 * b2f(u6.y) + w7 * b2f(u7.y);
      a2 += w0 * b2f(u0.z) + w1 * b2f(u1.z) + w2 * b2f(u2.z) + w3 * b2f(u3.z)
          + w4 * b2f(u4.z) + w5 * b2f(u5.z) + w6 * b2f(u6.z) + w7 * b2f(u7.z);
      a3 += w0 * b2f(u0.w) + w1 * b2f(u1.w) + w2 * b2f(u2.w) + w3 * b2f(u3.w)
          + w4 * b2f(u4.w) + w5 * b2f(u5.w) + w6 * b2f(u6.w) + w7 * b2f(u7.w);
    }
    for (; t < deg; ++t) {
      int s = col[beg + t];
      float w = __shfl(we, t) * inv;
      ushort4 u = *reinterpret_cast<const ushort4*>(&h[(size_t)s * 256 + lane * 4]);
      a0 += w * b2f(u.x); a1 += w * b2f(u.y);
      a2 += w * b2f(u.z); a3 += w * b2f(u.w);
    }
  } else {  // deg > 64: recompute weights (astronomically rare)
    for (int j = beg; j < end; ++j) {
      int s = col[j];
      float w = __expf(leaky(asrc[s] + ad)) * inv;
      ushort4 u = *reinterpret_cast<const ushort4*>(&h[(size_t)s * 256 + lane * 4]);
      a0 += w * b2f(u.x); a1 += w * b2f(u.y);
      a2 += w * b2f(u.z); a3 += w * b2f(u.w);
    }
  }
  float4 bv = *reinterpret_cast<const float4*>(&bias[lane * 4]);
  ushort4 o;
  o.x = f2b(fmaxf(a0 + bv.x, 0.f));
  o.y = f2b(fmaxf(a1 + bv.y, 0.f));
  o.z = f2b(fmaxf(a2 + bv.z, 0.f));
  o.w = f2b(fmaxf(a3 + bv.w, 0.f));
  *reinterpret_cast<ushort4*>(&out[(size_t)n * 256 + lane * 4]) = o;
}

// layer 2: lane = 1 channel (C=64); fused +bias, final fp32 output
__global__ __launch_bounds__(256) void fused_agg2(
    const ushort_t* __restrict__ h, const int* __restrict__ rowptr,
    const int* __restrict__ col, const float* __restrict__ asrc,
    const float* __restrict__ adst, const float* __restrict__ bias,
    float* __restrict__ out) {
  int n = blockIdx.x * 4 + (threadIdx.x >> 6);
  if (n >= N_NODES) return;
  int lane = threadIdx.x & 63;
  int beg = rowptr[n], end = rowptr[n + 1];
  int deg = end - beg;
  float ad = adst[n];
  float we = 0.f;
  if (lane < deg) we = __expf(leaky(asrc[col[beg + lane]] + ad));
  float ssum = we;
  for (int jj = beg + 64 + lane; jj < end; jj += 64)
    ssum += __expf(leaky(asrc[col[jj]] + ad));
#pragma unroll
  for (int off = 32; off; off >>= 1) ssum += __shfl_xor(ssum, off);
  float inv = 1.0f / ssum;
  float acc = 0.f;
  if (deg <= 64) {
    int t = 0;
    for (; t + 8 <= deg; t += 8) {
      int s0 = col[beg + t],     s1 = col[beg + t + 1];
      int s2 = col[beg + t + 2], s3 = col[beg + t + 3];
      int s4 = col[beg + t + 4], s5 = col[beg + t + 5];
      int s6 = col[beg + t + 6], s7 = col[beg + t + 7];
      float w0 = __shfl(we, t) * inv,     w1 = __shfl(we, t + 1) * inv;
      float w2 = __shfl(we, t + 2) * inv, w3 = __shfl(we, t + 3) * inv;
      float w4 = __shfl(we, t + 4) * inv, w5 = __shfl(we, t + 5) * inv;
      float w6 = __shfl(we, t + 6) * inv, w7 = __shfl(we, t + 7) * inv;
      ushort_t u0 = h[(size_t)s0 * 64 + lane];
      ushort_t u1 = h[(size_t)s1 * 64 + lane];
      ushort_t u2 = h[(size_t)s2 * 64 + lane];
      ushort_t u3 = h[(size_t)s3 * 64 + lane];
      ushort_t u4 = h[(size_t)s4 * 64 + lane];
      ushort_t u5 = h[(size_t)s5 * 64 + lane];
      ushort_t u6 = h[(size_t)s6 * 64 + lane];
      ushort_t u7 = h[(size_t)s7 * 64 + lane];
      acc += w0 * b2f(u0) + w1 * b2f(u1) + w2 * b2f(u2) + w3 * b2f(u3)
           + w4 * b2f(u4) + w5 * b2f(u5) + w6 * b2f(u6) + w7 * b2f(u7);
    }
    for (; t < deg; ++t) {
      float w = __shfl(we, t) * inv;
      acc += w * b2f(h[(size_t)col[beg + t] * 64 + lane]);
    }
  } else {
    for (int j = beg; j < end; ++j) {
      int s = col[j];
      float w = __expf(leaky(asrc[s] + ad)) * inv;
      acc += w * b2f(h[(size_t)s * 64 + lane]);
    }
  }
  out[(size_t)n * 64 + lane] = acc + bias[lane];
}

// ---------------- launch ----------------

extern "C" void kernel_launch(void* const* d_in, const int* in_sizes, int n_in,
                              void* d_out, int out_size, void* d_ws, size_t ws_size,
                              hipStream_t stream) {
  const float* x    = (const float*)d_in[0];
  const int*   ei   = (const int*)d_in[1];
  const float* W1   = (const float*)d_in[2];
  const float* a1s  = (const float*)d_in[3];
  const float* a1d  = (const float*)d_in[4];
  const float* b1   = (const float*)d_in[5];
  const float* W2   = (const float*)d_in[6];
  const float* a2s  = (const float*)d_in[7];
  const float* a2d  = (const float*)d_in[8];
  const float* b2   = (const float*)d_in[9];
  float* out = (float*)d_out;

  char* ws = (char*)d_ws;
  size_t off = 0;
  auto alloc = [&](size_t bytes) {
    void* p = ws + off;
    off += bytes;
    off = (off + 255) & ~(size_t)255;
    return p;
  };

  ushort_t* h1   = (ushort_t*)alloc((size_t)N_NODES * 256 * 2);  // bf16
  ushort_t* a1b  = (ushort_t*)alloc((size_t)N_NODES * 256 * 2);  // bf16 relu(agg1+b1)
  ushort_t* h2   = (ushort_t*)alloc((size_t)N_NODES * 64 * 2);   // bf16
  ushort_t* W1t  = (ushort_t*)alloc((size_t)256 * 128 * 2);
  ushort_t* W2t  = (ushort_t*)alloc((size_t)64 * 256 * 2);
  float* asrc1   = (float*)alloc((size_t)N_NODES * 4);
  float* adst1   = (float*)alloc((size_t)N_NODES * 4);
  float* asrc2   = (float*)alloc((size_t)N_NODES * 4);
  float* adst2   = (float*)alloc((size_t)N_NODES * 4);
  int*   deg     = (int*)alloc((size_t)N_NODES * 4);
  int*   rowptr  = (int*)alloc((size_t)(N_NODES + 1) * 4);
  int*   fillp   = (int*)alloc((size_t)N_NODES * 4);
  int*   col     = (int*)alloc((size_t)E_TOT * 4);
  int*   bsums   = (int*)alloc((size_t)SCAN_NB * 4);
  int*   boffs   = (int*)alloc((size_t)SCAN_NB * 4);

  const int edgeBlocks = (E_TOT + 255) / 256;
  const int nodeBlocks4 = (N_NODES + 3) / 4;
  const int gemmBlocksM = (N_NODES + 127) / 128;

  // CSR build
  hipMemsetAsync(deg, 0, (size_t)N_NODES * 4, stream);
  degree_kernel<<<edgeBlocks, 256, 0, stream>>>(ei, deg);
  scan_p1<<<SCAN_NB, 1024, 0, stream>>>(deg, bsums);
  scan_p2<<<1, 64, 0, stream>>>(bsums, boffs);
  scan_p3<<<SCAN_NB, 1024, 0, stream>>>(deg, boffs, rowptr, fillp);
  fill_kernel<<<edgeBlocks, 256, 0, stream>>>(ei, fillp, col);

  // weight prep
  transpose_cast<<<(256 * 128 + 255) / 256, 256, 0, stream>>>(W1, W1t, 128, 256);
  transpose_cast<<<(64 * 256 + 255) / 256, 256, 0, stream>>>(W2, W2t, 256, 64);

  // layer 1: h1 = bf16(x) @ bf16(W1)
  mfma_gemm<2, 2, 128, true><<<dim3(gemmBlocksM, 2), 256, 0, stream>>>(
      x, W1t, h1, N_NODES, 256);
  alpha_kernel<256><<<nodeBlocks4, 256, 0, stream>>>(h1, a1s, a1d, asrc1, adst1);
  fused_agg1<<<nodeBlocks4, 256, 0, stream>>>(h1, rowptr, col, asrc1, adst1, b1, a1b);

  // layer 2: h2 = a1b @ bf16(W2)
  mfma_gemm<4, 1, 256, false><<<dim3(gemmBlocksM, 1), 256, 0, stream>>>(
      a1b, W2t, h2, N_NODES, 64);
  alpha_kernel<64><<<nodeBlocks4, 256, 0, stream>>>(h2, a2s, a2d, asrc2, adst2);
  fused_agg2<<<nodeBlocks4, 256, 0, stream>>>(h2, rowptr, col, asrc2, adst2, b2, out);
}